// Round 6
// baseline (279.845 us; speedup 1.0000x reference)
//
#include <hip/hip_runtime.h>

#define N_SEQ 1024
#define B_SZ 8
#define C_DIM 256
#define K_HEADS 4
#define FF_DIM 2048

typedef short s16x8 __attribute__((ext_vector_type(8)));
typedef float f32x4v __attribute__((ext_vector_type(4)));
typedef float f32x16 __attribute__((ext_vector_type(16)));
typedef unsigned int u32x4 __attribute__((ext_vector_type(4)));

#define GLOAD_LDS16(src, dst)                                                              \
    __builtin_amdgcn_global_load_lds((const __attribute__((address_space(1))) void*)(src), \
                                     (__attribute__((address_space(3))) void*)(dst), 16, 0, 0)

__device__ __forceinline__ unsigned short f2bf(float f) {
    unsigned u = __builtin_bit_cast(unsigned, f);
    u += 0x7FFFu + ((u >> 16) & 1u);
    return (unsigned short)(u >> 16);
}
__device__ __forceinline__ float bf2f(unsigned short h) {
    unsigned u = ((unsigned)h) << 16;
    return __builtin_bit_cast(float, u);
}

// ---------------- prep kernels ----------------

__global__ __launch_bounds__(256) void prep_q_kernel(const float* __restrict__ src,
                                                     const float* __restrict__ pos,
                                                     unsigned short* __restrict__ qb) {
    int t = blockIdx.x * 256 + threadIdx.x;
    int i4 = t * 4;
    float4 s = *reinterpret_cast<const float4*>(src + i4);
    float4 p = *reinterpret_cast<const float4*>(pos + i4);
    int n = i4 >> 11;
    int rem = i4 & 2047;
    int b = rem >> 8;
    int c = rem & 255;
    int out = (b * N_SEQ + n) * C_DIM + c;
    *reinterpret_cast<ushort4*>(qb + out) = make_ushort4(
        f2bf((s.x + p.x) * 0.0625f), f2bf((s.y + p.y) * 0.0625f),
        f2bf((s.z + p.z) * 0.0625f), f2bf((s.w + p.w) * 0.0625f));
}

// One block per (k,b,ntile of 64): writes kb row-major (+pos) and V in
// fragment-tile layout: vfrag[pr][tile(32kv)][channel 256][kv-in-tile 32].
__global__ __launch_bounds__(256) void prep_kv_kernel(const float* __restrict__ matched,
                                                      const float* __restrict__ pos,
                                                      unsigned short* __restrict__ kb,
                                                      unsigned short* __restrict__ vfrag) {
    __shared__ unsigned short Vl[64][256];
    int blk = blockIdx.x;
    int nt = blk & 15, pr = blk >> 4;          // pr = k*8+b
    int k = pr >> 3, b = pr & 7;
    int n0 = nt * 64;
    int t = threadIdx.x;
    int c4 = (t & 63) * 4;
#pragma unroll
    for (int r = 0; r < 16; r++) {
        int nl = (t >> 6) * 16 + r;
        int n = n0 + nl;
        size_t mi = ((size_t)(k * N_SEQ + n) * B_SZ + b) * C_DIM + c4;
        float4 m = *reinterpret_cast<const float4*>(matched + mi);
        float4 p = *reinterpret_cast<const float4*>(pos + ((size_t)n * B_SZ + b) * C_DIM + c4);
        *reinterpret_cast<ushort4*>(kb + ((size_t)pr * N_SEQ + n) * C_DIM + c4) =
            make_ushort4(f2bf(m.x + p.x), f2bf(m.y + p.y), f2bf(m.z + p.z), f2bf(m.w + p.w));
        *reinterpret_cast<ushort4*>(&Vl[nl][c4]) =
            make_ushort4(f2bf(m.x), f2bf(m.y), f2bf(m.z), f2bf(m.w));
    }
    __syncthreads();
    int j8 = t & 3, cbase = t >> 2;
#pragma unroll
    for (int h = 0; h < 2; h++) {
        unsigned short* tb = vfrag + ((size_t)(pr * 32 + nt * 2 + h)) * 8192;
#pragma unroll
        for (int kk = 0; kk < 4; kk++) {
            int c = cbase + 64 * kk;
            s16x8 v;
#pragma unroll
            for (int e = 0; e < 8; e++) v[e] = (short)Vl[h * 32 + j8 * 8 + e][c];
            *reinterpret_cast<s16x8*>(tb + (size_t)(t + 256 * kk) * 8) = v;
        }
    }
}

__global__ __launch_bounds__(256) void transpose_w_kernel(const float* __restrict__ W,
                                                          unsigned short* __restrict__ Wt,
                                                          int R, int Cn) {
    int idx = blockIdx.x * 256 + threadIdx.x;
    int c = idx / R;
    int r = idx - c * R;
    Wt[idx] = f2bf(W[(size_t)r * Cn + c]);
}

// ---------------- flash attention, 32x32x16 MFMA, KV-split x2 ----------------
// grid = 512 blocks, 256 threads (4 waves x 32 q-rows). S^T = K Q^T; O = P V.
__global__ __launch_bounds__(256, 2) void attn_kernel(const unsigned short* __restrict__ qb,
                                                      const unsigned short* __restrict__ kb,
                                                      const unsigned short* __restrict__ vfrag,
                                                      const float* __restrict__ mask,
                                                      unsigned short* __restrict__ op0,
                                                      unsigned short* __restrict__ op1,
                                                      float2* __restrict__ mlb) {
    __shared__ unsigned short Kl[2][8192];   // 32 KB: [32 kv][256 c], XOR ci^=(ci>>5)&7
    __shared__ unsigned short Vl[2][8192];   // 32 KB: [256 ch][32 kv], XOR ci^=(ci>>3)&7

    // XCD mapping: same-XCD for the 8 qt sharing a (pr,half) K/V panel and the
    // 4 kidx sharing a (b,half) mask slice.
    int bx = blockIdx.x;
    int x = bx & 7, j = bx >> 3;
    int hb = x + 8 * (j & 1);
    int b = hb & 7, half = hb >> 3;
    int j2 = j >> 1;
    int kidx = j2 & 3, qt = j2 >> 2;         // qt 0..7
    int pr = kidx * 8 + b;

    int tid = threadIdx.x, wid = tid >> 6, lane = tid & 63;
    int l31 = lane & 31, hi = lane >> 5;
    int q0 = qt * 128 + wid * 32;            // this wave's q base; lane's q = q0+l31
    int kvh = half * 512;

    // Q fragments (B-operand): Q[q=l31][c = ks*16 + hi*8 + i]
    s16x8 qf[16];
    const unsigned short* qrow = qb + ((size_t)(b * N_SEQ + q0 + l31)) * C_DIM + hi * 8;
#pragma unroll
    for (int ks = 0; ks < 16; ks++) qf[ks] = *reinterpret_cast<const s16x8*>(qrow + ks * 16);

    f32x16 oacc[8];
#pragma unroll
    for (int ct = 0; ct < 8; ct++)
#pragma unroll
        for (int r = 0; r < 16; r++) oacc[ct][r] = 0.f;
    float mrun = -3e38f, lrun = 0.f;

    const unsigned short* kbp = kb + ((size_t)pr * N_SEQ + kvh) * C_DIM;
    const unsigned short* vfp = vfrag + ((size_t)(pr * 32 + half * 16)) * 8192;
    const float* mbase = mask + ((size_t)b * N_SEQ + q0 + l31) * N_SEQ + kvh;

    auto stage_k = [&](int kv0, unsigned short* buf) {
#pragma unroll
        for (int i = 0; i < 4; i++) {
            int ci = (wid * 4 + i) * 64 + lane;
            int sci = ci ^ ((ci >> 5) & 7);          // kv-row involution
            GLOAD_LDS16(kbp + (size_t)kv0 * C_DIM + sci * 8, buf + (wid * 4 + i) * 512);
        }
    };
    auto stage_v = [&](int tile, unsigned short* buf) {
        const unsigned short* vsrc = vfp + (size_t)tile * 8192;
#pragma unroll
        for (int i = 0; i < 4; i++) {
            int ci = (wid * 4 + i) * 64 + lane;
            int sci = ci ^ ((ci >> 3) & 7);          // ch-row involution
            GLOAD_LDS16(vsrc + sci * 8, buf + (wid * 4 + i) * 512);
        }
    };

    stage_k(0, &Kl[0][0]);
    stage_v(0, &Vl[0][0]);

    int kswz = l31 & 7;
    int vswz = (l31 >> 1) & 7;

    for (int t = 0; t < 16; t++) {
        int cur = t & 1;
        int kv0 = t * 32;
        __syncthreads();                             // tiles[cur] ready (vmcnt drained)
        if (t + 1 < 16) {
            stage_k(kv0 + 32, &Kl[cur ^ 1][0]);
            stage_v(t + 1, &Vl[cur ^ 1][0]);
        }
        // mask (consumed after QK; row fixed per lane, cols crow)
        float mk[16];
#pragma unroll
        for (int r = 0; r < 16; r++)
            mk[r] = mbase[kv0 + (r & 3) + 8 * (r >> 2) + 4 * hi];

        // S^T = K Q^T : A = K[kv=l31][c], B = Q^T; C/D row=kv=crow, col=q=l31
        f32x16 s;
#pragma unroll
        for (int r = 0; r < 16; r++) s[r] = 0.f;
        const unsigned short* KlB = &Kl[cur][0];
        __builtin_amdgcn_s_setprio(1);
#pragma unroll
        for (int ks = 0; ks < 16; ks++) {
            int ck = (l31 * 32 + ks * 2 + hi) ^ kswz;
            s16x8 kf = *reinterpret_cast<const s16x8*>(KlB + ck * 8);
            s = __builtin_amdgcn_mfma_f32_32x32x16_bf16(kf, qf[ks], s, 0, 0, 0);
        }
        __builtin_amdgcn_s_setprio(0);
#pragma unroll
        for (int r = 0; r < 16; r++) s[r] += mk[r];

        // softmax over kv (in-lane 16 + hi-swap); stats live in q=l31 space
        float pm = s[0];
#pragma unroll
        for (int r = 1; r < 16; r++) pm = fmaxf(pm, s[r]);
        pm = fmaxf(pm, __shfl_xor(pm, 32));
        if (__any(pm > mrun + 8.f)) {                // defer-max
            float mn = fmaxf(mrun, pm);
            float sc = __expf(mrun - mn);
            mrun = mn;
            lrun *= sc;
            float scr[16];
#pragma unroll
            for (int r = 0; r < 16; r++) scr[r] = __shfl(sc, (r & 3) + 8 * (r >> 2) + 4 * hi);
#pragma unroll
            for (int ct = 0; ct < 8; ct++)
#pragma unroll
                for (int r = 0; r < 16; r++) oacc[ct][r] *= scr[r];
        }
        float p[16], ps = 0.f;
#pragma unroll
        for (int r = 0; r < 16; r++) {
            p[r] = __expf(s[r] - mrun);
            ps += p[r];
        }
        ps += __shfl_xor(ps, 32);
        lrun += ps;

        // P -> A-fragment (in-register): pack kv pairs, hi-swap, select
        unsigned pa[8], po[8];
#pragma unroll
        for (int w = 0; w < 8; w++)
            pa[w] = (unsigned)f2bf(p[2 * w]) | ((unsigned)f2bf(p[2 * w + 1]) << 16);
#pragma unroll
        for (int w = 0; w < 8; w++) po[w] = (unsigned)__shfl_xor((int)pa[w], 32);
        u32x4 w0v = hi ? (u32x4){po[2], po[3], pa[2], pa[3]}
                       : (u32x4){pa[0], pa[1], po[0], po[1]};
        u32x4 w1v = hi ? (u32x4){po[6], po[7], pa[6], pa[7]}
                       : (u32x4){pa[4], pa[5], po[4], po[5]};
        s16x8 pf0 = __builtin_bit_cast(s16x8, w0v);
        s16x8 pf1 = __builtin_bit_cast(s16x8, w1v);

        // O += P V : A = P[q=l31][kv], B = V^T[ch=l31][kv]; C/D row=q=crow, col=ch
        const unsigned short* VlB = &Vl[cur][0];
        __builtin_amdgcn_s_setprio(1);
#pragma unroll
        for (int ct = 0; ct < 8; ct++) {
            int cl0 = (ct * 128 + l31 * 4 + hi) ^ vswz;
            int cl1 = (ct * 128 + l31 * 4 + 2 + hi) ^ vswz;
            s16x8 vf0 = *reinterpret_cast<const s16x8*>(VlB + cl0 * 8);
            s16x8 vf1 = *reinterpret_cast<const s16x8*>(VlB + cl1 * 8);
            oacc[ct] = __builtin_amdgcn_mfma_f32_32x32x16_bf16(pf0, vf0, oacc[ct], 0, 0, 0);
            oacc[ct] = __builtin_amdgcn_mfma_f32_32x32x16_bf16(pf1, vf1, oacc[ct], 0, 0, 0);
        }
        __builtin_amdgcn_s_setprio(0);
    }

    float inv = 1.0f / lrun;
    float invr[16];
#pragma unroll
    for (int r = 0; r < 16; r++) invr[r] = __shfl(inv, (r & 3) + 8 * (r >> 2) + 4 * hi);
    unsigned short* Op = half ? op1 : op0;
    size_t obase = ((size_t)(b * N_SEQ + q0)) * (K_HEADS * C_DIM) + kidx * C_DIM + l31;
#pragma unroll
    for (int ct = 0; ct < 8; ct++)
#pragma unroll
        for (int r = 0; r < 16; r++) {
            int qoff = (r & 3) + 8 * (r >> 2) + 4 * hi;
            Op[obase + (size_t)qoff * (K_HEADS * C_DIM) + ct * 32] =
                f2bf(oacc[ct][r] * invr[r]);
        }
    if (lane < 32)
        mlb[((size_t)(half * 4 + kidx) * 8 + b) * N_SEQ + q0 + l31] = make_float2(mrun, lrun);
}

// ---------------- combine two KV-half partials ----------------
__global__ __launch_bounds__(256) void combine_kernel(const unsigned short* __restrict__ op0,
                                                      const unsigned short* __restrict__ op1,
                                                      const float2* __restrict__ mlb,
                                                      unsigned short* __restrict__ att) {
    int t = blockIdx.x * 256 + threadIdx.x;
    int kidx = (t >> 5) & 3;
    int bn = t >> 7;
    int n = bn & 1023, b = bn >> 10;
    float2 e0 = mlb[((size_t)kidx * 8 + b) * N_SEQ + n];
    float2 e1 = mlb[((size_t)(4 + kidx) * 8 + b) * N_SEQ + n];
    float M = fmaxf(e0.x, e1.x);
    float w0 = e0.y * __expf(e0.x - M);
    float w1 = e1.y * __expf(e1.x - M);
    float r = 1.0f / (w0 + w1);
    w0 *= r;
    w1 *= r;
    s16x8 a = *reinterpret_cast<const s16x8*>(op0 + (size_t)t * 8);
    s16x8 c = *reinterpret_cast<const s16x8*>(op1 + (size_t)t * 8);
    s16x8 o;
#pragma unroll
    for (int i = 0; i < 8; i++)
        o[i] = (short)f2bf(w0 * bf2f((unsigned short)a[i]) + w1 * bf2f((unsigned short)c[i]));
    *reinterpret_cast<s16x8*>(att + (size_t)t * 8) = o;
}

// ---------------- GEMM: C = A(MxK) * Bt(NxK)^T + bias ----------------
template <int BM, int BN, int RELU, int OUTBF>
__global__ __launch_bounds__(256) void gemm_bt_kernel(const unsigned short* __restrict__ A,
                                                      const unsigned short* __restrict__ Bt,
                                                      const float* __restrict__ bias,
                                                      float* __restrict__ Cf,
                                                      unsigned short* __restrict__ Cb,
                                                      int M, int Nn, int Kd) {
    constexpr int WAVES_N = (BM == 128) ? 2 : 4;
    constexpr int WN = BN / WAVES_N;
    constexpr int NT = WN / 16;
    constexpr int TILE = (BM + BN) * 64;
    constexpr int CALLS = (BM + BN) / 32;
    __shared__ unsigned short Sl[2][TILE];
    int tm0 = blockIdx.y * BM, tn0 = blockIdx.x * BN;
    int tid = threadIdx.x, wid = tid >> 6, lane = tid & 63;
    int l15 = lane & 15, lg = lane >> 4;
    int wm = (wid / WAVES_N) * 64, wn = (wid % WAVES_N) * WN;

    f32x4v acc[4][NT];
#pragma unroll
    for (int i = 0; i < 4; i++)
#pragma unroll
        for (int j = 0; j < NT; j++) acc[i][j] = (f32x4v){0.f, 0.f, 0.f, 0.f};

    auto stage = [&](int k0, unsigned short* buf) {
#pragma unroll
        for (int i = 0; i < CALLS; i++) {
            int chb = (i * 4 + wid) * 64;
            int ch = chb + lane;
            const unsigned short* src;
            if (chb < BM * 8) {
                int r = ch >> 3;
                int c8 = ((ch & 7) * 8) ^ ((r & 7) << 3);
                src = A + (size_t)(tm0 + r) * Kd + k0 + c8;
            } else {
                int ch2 = ch - BM * 8;
                int r = ch2 >> 3;
                int c8 = ((ch2 & 7) * 8) ^ ((r & 7) << 3);
                src = Bt + (size_t)(tn0 + r) * Kd + k0 + c8;
            }
            GLOAD_LDS16(src, buf + chb * 8);
        }
    };

    stage(0, &Sl[0][0]);
    int nk = Kd >> 6;
    int swz = (l15 & 7) << 3;
    for (int kt = 0; kt < nk; kt++) {
        int cur = kt & 1;
        __syncthreads();
        if (kt + 1 < nk) stage((kt + 1) * 64, &Sl[cur ^ 1][0]);
        const unsigned short* SA = &Sl[cur][0];
        const unsigned short* SB = SA + BM * 64;
        s16x8 af[4][2], bf[NT][2];
#pragma unroll
        for (int mt = 0; mt < 4; mt++)
#pragma unroll
            for (int h = 0; h < 2; h++)
                af[mt][h] = *reinterpret_cast<const s16x8*>(
                    SA + (wm + mt * 16 + l15) * 64 + ((h * 32 + lg * 8) ^ swz));
#pragma unroll
        for (int nt = 0; nt < NT; nt++)
#pragma unroll
            for (int h = 0; h < 2; h++)
                bf[nt][h] = *reinterpret_cast<const s16x8*>(
                    SB + (wn + nt * 16 + l15) * 64 + ((h * 32 + lg * 8) ^ swz));
        __builtin_amdgcn_s_setprio(1);
#pragma unroll
        for (int mt = 0; mt < 4; mt++)
#pragma unroll
            for (int nt = 0; nt < NT; nt++) {
                acc[mt][nt] = __builtin_amdgcn_mfma_f32_16x16x32_bf16(af[mt][0], bf[nt][0], acc[mt][nt], 0, 0, 0);
                acc[mt][nt] = __builtin_amdgcn_mfma_f32_16x16x32_bf16(af[mt][1], bf[nt][1], acc[mt][nt], 0, 0, 0);
            }
        __builtin_amdgcn_s_setprio(0);
    }

#pragma unroll
    for (int mt = 0; mt < 4; mt++) {
#pragma unroll
        for (int nt = 0; nt < NT; nt++) {
#pragma unroll
            for (int j = 0; j < 4; j++) {
                int row = tm0 + wm + mt * 16 + lg * 4 + j;
                int col = tn0 + wn + nt * 16 + l15;
                float v = acc[mt][nt][j] + bias[col];
                if (RELU) v = fmaxf(v, 0.f);
                if (OUTBF) Cb[(size_t)row * Nn + col] = f2bf(v);
                else       Cf[(size_t)row * Nn + col] = v;
            }
        }
    }
}

// ---------------- fused residual + LayerNorm ----------------
__global__ __launch_bounds__(256) void ln1_kernel(const float* __restrict__ src,
                                                  const float* __restrict__ recT,
                                                  const float* __restrict__ g,
                                                  const float* __restrict__ be,
                                                  float* __restrict__ outf,
                                                  unsigned short* __restrict__ outb) {
    int r = blockIdx.x * 4 + (threadIdx.x >> 6);
    int lane = threadIdx.x & 63;
    int n = r >> 3, b = r & 7;
    int c = lane * 4;
    float4 xs = *reinterpret_cast<const float4*>(src + (size_t)r * C_DIM + c);
    float4 xr = *reinterpret_cast<const float4*>(recT + ((size_t)(b * N_SEQ + n)) * C_DIM + c);
    float x[4] = {xs.x + xr.x, xs.y + xr.y, xs.z + xr.z, xs.w + xr.w};
    float s = x[0] + x[1] + x[2] + x[3];
    float q = x[0] * x[0] + x[1] * x[1] + x[2] * x[2] + x[3] * x[3];
#pragma unroll
    for (int d = 1; d < 64; d <<= 1) {
        s += __shfl_xor(s, d);
        q += __shfl_xor(q, d);
    }
    float mean = s * (1.f / 256.f);
    float var = q * (1.f / 256.f) - mean * mean;
    float rstd = rsqrtf(var + 1e-5f);
    float4 gv = *reinterpret_cast<const float4*>(g + c);
    float4 bv = *reinterpret_cast<const float4*>(be + c);
    float y0 = (x[0] - mean) * rstd * gv.x + bv.x;
    float y1 = (x[1] - mean) * rstd * gv.y + bv.y;
    float y2 = (x[2] - mean) * rstd * gv.z + bv.z;
    float y3 = (x[3] - mean) * rstd * gv.w + bv.w;
    *reinterpret_cast<float4*>(outf + (size_t)r * C_DIM + c) = make_float4(y0, y1, y2, y3);
    *reinterpret_cast<ushort4*>(outb + (size_t)r * C_DIM + c) =
        make_ushort4(f2bf(y0), f2bf(y1), f2bf(y2), f2bf(y3));
}

__global__ __launch_bounds__(256) void ln2_kernel(const float* __restrict__ rec1f,
                                                  const float* __restrict__ ffn,
                                                  const float* __restrict__ g,
                                                  const float* __restrict__ be,
                                                  float* __restrict__ out) {
    int r = blockIdx.x * 4 + (threadIdx.x >> 6);
    int lane = threadIdx.x & 63;
    int c = lane * 4;
    size_t base = (size_t)r * C_DIM + c;
    float4 xa = *reinterpret_cast<const float4*>(rec1f + base);
    float4 xb = *reinterpret_cast<const float4*>(ffn + base);
    float x[4] = {xa.x + xb.x, xa.y + xb.y, xa.z + xb.z, xa.w + xb.w};
    float s = x[0] + x[1] + x[2] + x[3];
    float q = x[0] * x[0] + x[1] * x[1] + x[2] * x[2] + x[3] * x[3];
#pragma unroll
    for (int d = 1; d < 64; d <<= 1) {
        s += __shfl_xor(s, d);
        q += __shfl_xor(q, d);
    }
    float mean = s * (1.f / 256.f);
    float var = q * (1.f / 256.f) - mean * mean;
    float rstd = rsqrtf(var + 1e-5f);
    float4 gv = *reinterpret_cast<const float4*>(g + c);
    float4 bv = *reinterpret_cast<const float4*>(be + c);
    *reinterpret_cast<float4*>(out + base) = make_float4(
        (x[0] - mean) * rstd * gv.x + bv.x,
        (x[1] - mean) * rstd * gv.y + bv.y,
        (x[2] - mean) * rstd * gv.z + bv.z,
        (x[3] - mean) * rstd * gv.w + bv.w);
}

// ---------------- launch ----------------

extern "C" void kernel_launch(void* const* d_in, const int* in_sizes, int n_in,
                              void* d_out, int out_size, void* d_ws, size_t ws_size,
                              hipStream_t stream) {
    const float* src   = (const float*)d_in[0];
    const float* match = (const float*)d_in[1];
    const float* pos   = (const float*)d_in[2];
    const float* mask  = (const float*)d_in[3];
    const float* Wagg  = (const float*)d_in[4];
    const float* bagg  = (const float*)d_in[5];
    const float* W1    = (const float*)d_in[6];
    const float* b1    = (const float*)d_in[7];
    const float* W2    = (const float*)d_in[8];
    const float* b2    = (const float*)d_in[9];
    const float* g1    = (const float*)d_in[10];
    const float* be1   = (const float*)d_in[11];
    const float* g2    = (const float*)d_in[12];
    const float* be2   = (const float*)d_in[13];

    char* ws = (char*)d_ws;
    unsigned short* qb    = (unsigned short*)(ws + 0);          //  4 MB (B,N,C) bf16 pre-scaled
    unsigned short* kb    = (unsigned short*)(ws + 4194304);    // 16 MB (K*B,N,C) bf16
    unsigned short* vfrag = (unsigned short*)(ws + 20971520);   // 16 MB V fragment tiles
    unsigned short* att   = (unsigned short*)(ws + 37748736);   // 16 MB (B,N,K*C) bf16; = op0
    float*          rec_t = (float*)(ws + 57147392);            // 8 MB (B*N,C) f32
    float*          rec1f = (float*)(ws + 65536000);            // 8 MB (N*B,C) f32
    unsigned short* rec1b = (unsigned short*)(ws + 73924608);   // 4 MB bf16
    unsigned short* WaggT = (unsigned short*)(ws + 54525952);   // 0.5 MB
    unsigned short* W1T   = (unsigned short*)(ws + 55050240);   // 1 MB
    unsigned short* W2T   = (unsigned short*)(ws + 56098816);   // 1 MB
    // attention-phase aliases (dead regions during attn):
    unsigned short* op0   = att;                                // 16 MB partial half0
    unsigned short* op1   = (unsigned short*)(ws + 57147392);   // 16 MB partial half1
    float2*         mlb   = (float2*)(ws + 73924608);           // 512 KB (over rec1b)
    unsigned short* hid   = (unsigned short*)(ws + 4194304);    // 32 MB, aliases kb+vfrag
    float*          ffn   = (float*)(ws + 57147392);            // 8 MB, aliases rec_t
    float* outp = (float*)d_out;

    prep_q_kernel<<<2048, 256, 0, stream>>>(src, pos, qb);
    prep_kv_kernel<<<512, 256, 0, stream>>>(match, pos, kb, vfrag);
    transpose_w_kernel<<<1024, 256, 0, stream>>>(Wagg, WaggT, K_HEADS * C_DIM, C_DIM);
    transpose_w_kernel<<<2048, 256, 0, stream>>>(W1, W1T, C_DIM, FF_DIM);
    transpose_w_kernel<<<2048, 256, 0, stream>>>(W2, W2T, FF_DIM, C_DIM);

    attn_kernel<<<512, 256, 0, stream>>>(qb, kb, vfrag, mask, op0, op1, mlb);
    combine_kernel<<<4096, 256, 0, stream>>>(op0, op1, mlb, att);

    gemm_bt_kernel<64, 128, 0, 0><<<dim3(2, 128), 256, 0, stream>>>(
        att, WaggT, bagg, rec_t, nullptr, B_SZ * N_SEQ, C_DIM, K_HEADS * C_DIM);
    ln1_kernel<<<2048, 256, 0, stream>>>(src, rec_t, g1, be1, rec1f, rec1b);
    gemm_bt_kernel<128, 128, 1, 1><<<dim3(16, 64), 256, 0, stream>>>(
        rec1b, W1T, b1, nullptr, hid, N_SEQ * B_SZ, FF_DIM, C_DIM);
    gemm_bt_kernel<64, 128, 0, 0><<<dim3(2, 128), 256, 0, stream>>>(
        hid, W2T, b2, ffn, nullptr, N_SEQ * B_SZ, C_DIM, FF_DIM);
    ln2_kernel<<<2048, 256, 0, stream>>>(rec1f, ffn, g2, be2, outp);
}

// Round 7
// 217.382 us; speedup vs baseline: 1.2873x; 1.2873x over previous
//
#include <hip/hip_runtime.h>

#define N_SEQ 1024
#define B_SZ 8
#define C_DIM 256
#define K_HEADS 4
#define FF_DIM 2048

typedef short s16x8 __attribute__((ext_vector_type(8)));
typedef float f32x4v __attribute__((ext_vector_type(4)));

#define GLOAD_LDS16(src, dst)                                                              \
    __builtin_amdgcn_global_load_lds((const __attribute__((address_space(1))) void*)(src), \
                                     (__attribute__((address_space(3))) void*)(dst), 16, 0, 0)

__device__ __forceinline__ unsigned short f2bf(float f) {
    unsigned u = __builtin_bit_cast(unsigned, f);
    u += 0x7FFFu + ((u >> 16) & 1u);
    return (unsigned short)(u >> 16);
}
__device__ __forceinline__ float bf2f(unsigned short h) {
    unsigned u = ((unsigned)h) << 16;
    return __builtin_bit_cast(float, u);
}

// ---------------- prep kernels ----------------

__global__ __launch_bounds__(256) void prep_q_kernel(const float* __restrict__ src,
                                                     const float* __restrict__ pos,
                                                     unsigned short* __restrict__ qb) {
    int t = blockIdx.x * 256 + threadIdx.x;
    int i4 = t * 4;
    float4 s = *reinterpret_cast<const float4*>(src + i4);
    float4 p = *reinterpret_cast<const float4*>(pos + i4);
    int n = i4 >> 11;
    int rem = i4 & 2047;
    int b = rem >> 8;
    int c = rem & 255;
    int out = (b * N_SEQ + n) * C_DIM + c;
    *reinterpret_cast<ushort4*>(qb + out) = make_ushort4(
        f2bf((s.x + p.x) * 0.0625f), f2bf((s.y + p.y) * 0.0625f),
        f2bf((s.z + p.z) * 0.0625f), f2bf((s.w + p.w) * 0.0625f));
}

// One block per (k,b,ntile of 64): writes kb row-major (+pos) and V in
// fragment-tile layout: vfrag[pr][tile(32kv)][channel 256][kv-in-tile 32].
__global__ __launch_bounds__(256) void prep_kv_kernel(const float* __restrict__ matched,
                                                      const float* __restrict__ pos,
                                                      unsigned short* __restrict__ kb,
                                                      unsigned short* __restrict__ vfrag) {
    __shared__ unsigned short Vl[64][256];
    int blk = blockIdx.x;
    int nt = blk & 15, pr = blk >> 4;          // pr = k*8+b
    int k = pr >> 3, b = pr & 7;
    int n0 = nt * 64;
    int t = threadIdx.x;
    int c4 = (t & 63) * 4;
#pragma unroll
    for (int r = 0; r < 16; r++) {
        int nl = (t >> 6) * 16 + r;
        int n = n0 + nl;
        size_t mi = ((size_t)(k * N_SEQ + n) * B_SZ + b) * C_DIM + c4;
        float4 m = *reinterpret_cast<const float4*>(matched + mi);
        float4 p = *reinterpret_cast<const float4*>(pos + ((size_t)n * B_SZ + b) * C_DIM + c4);
        *reinterpret_cast<ushort4*>(kb + ((size_t)pr * N_SEQ + n) * C_DIM + c4) =
            make_ushort4(f2bf(m.x + p.x), f2bf(m.y + p.y), f2bf(m.z + p.z), f2bf(m.w + p.w));
        *reinterpret_cast<ushort4*>(&Vl[nl][c4]) =
            make_ushort4(f2bf(m.x), f2bf(m.y), f2bf(m.z), f2bf(m.w));
    }
    __syncthreads();
    int j8 = t & 3, cbase = t >> 2;
#pragma unroll
    for (int h = 0; h < 2; h++) {
        unsigned short* tb = vfrag + ((size_t)(pr * 32 + nt * 2 + h)) * 8192;
#pragma unroll
        for (int kk = 0; kk < 4; kk++) {
            int c = cbase + 64 * kk;
            s16x8 v;
#pragma unroll
            for (int e = 0; e < 8; e++) v[e] = (short)Vl[h * 32 + j8 * 8 + e][c];
            *reinterpret_cast<s16x8*>(tb + (size_t)(t + 256 * kk) * 8) = v;
        }
    }
}

__global__ __launch_bounds__(256) void transpose_w_kernel(const float* __restrict__ W,
                                                          unsigned short* __restrict__ Wt,
                                                          int R, int Cn) {
    int idx = blockIdx.x * 256 + threadIdx.x;
    int c = idx / R;
    int r = idx - c * R;
    Wt[idx] = f2bf(W[(size_t)r * Cn + c]);
}

// ---------------- flash attention (KV-split x2, 8-wave blocks) ----------------
// grid = 512 blocks x 512 threads (8 waves x 16 q-rows = 128 q / block).
// XCD: b = bx&7 -> each XCD owns one batch's mask/Q; kidx+qt sharers co-XCD.
__global__ __launch_bounds__(512, 4) void attn_kernel(const unsigned short* __restrict__ qb,
                                                      const unsigned short* __restrict__ kb,
                                                      const unsigned short* __restrict__ vfrag,
                                                      const float* __restrict__ mask,
                                                      unsigned short* __restrict__ op0,
                                                      unsigned short* __restrict__ op1,
                                                      float2* __restrict__ mlb) {
    __shared__ unsigned short Kl[2][8192];       // 32 KB: K tile, XOR-swizzled content
    __shared__ unsigned short VlF[2][8192];      // 32 KB: V fragment tile [ch 256][kv 32]
    __shared__ unsigned short Pl[8][16][36];     // 9.2 KB: wave-private P

    int bx = blockIdx.x;
    int b = bx & 7;
    int r2 = bx >> 3;
    int half = r2 & 1;
    int kidx = (r2 >> 1) & 3;
    int qt = r2 >> 3;                            // 0..7
    int pr = kidx * 8 + b;

    int tid = threadIdx.x, wid = tid >> 6, lane = tid & 63;
    int l15 = lane & 15, lg = lane >> 4;
    int q0 = qt * 128 + wid * 16;
    int kvh = half * 512;

    // Q fragments
    s16x8 qf[8];
    const unsigned short* qrow = qb + ((size_t)(b * N_SEQ + q0 + l15)) * C_DIM + lg * 8;
#pragma unroll
    for (int cc = 0; cc < 8; cc++) qf[cc] = *reinterpret_cast<const s16x8*>(qrow + cc * 32);

    f32x4v oacc[16];
#pragma unroll
    for (int i = 0; i < 16; i++) oacc[i] = (f32x4v){0.f, 0.f, 0.f, 0.f};
    float mrun = -3e38f, lrun = 0.f;

    const unsigned short* kbp = kb + (size_t)pr * N_SEQ * C_DIM;
    const unsigned short* vfp = vfrag + ((size_t)(pr * 32 + half * 16)) * 8192;
    const float* mrow = mask + ((size_t)b * N_SEQ + q0 + l15) * N_SEQ + kvh;

    auto stage_k = [&](int kv0, unsigned short* buf) {
#pragma unroll
        for (int i = 0; i < 2; i++) {
            int idx = wid * 2 + i;               // 0..15
            int ch = idx * 64 + lane;
            int r = ch >> 5;
            int ce = ((ch & 31) * 8) ^ ((r & 7) << 3);
            GLOAD_LDS16(kbp + (size_t)(kvh + kv0 + r) * C_DIM + ce, &buf[idx * 512]);
        }
    };
    auto stage_v = [&](int tile, unsigned short* buf) {
        const unsigned short* vsrc = vfp + (size_t)tile * 8192;
#pragma unroll
        for (int i = 0; i < 2; i++) {
            int cb = (wid * 2 + i) * 64;
            GLOAD_LDS16(vsrc + (size_t)(cb + lane) * 8, &buf[cb * 8]);
        }
    };

    // prologue: tile 0 K+V via gload_lds; mask tile 0 into regs
    stage_k(0, &Kl[0][0]);
    stage_v(0, &VlF[0][0]);
    f32x4v mc0 = *reinterpret_cast<const f32x4v*>(mrow + lg * 4);
    f32x4v mc1 = *reinterpret_cast<const f32x4v*>(mrow + 16 + lg * 4);

    int swz = (l15 & 7) << 3;
    for (int t = 0; t < 16; t++) {
        int cur = t & 1;
        int kv0 = t * 32;
        __syncthreads();                         // drains prefetch t; buffers [cur] ready
        // issue prefetch t+1 immediately (full-iter latency coverage)
        if (t + 1 < 16) {
            stage_k(kv0 + 32, &Kl[cur ^ 1][0]);
            stage_v(t + 1, &VlF[cur ^ 1][0]);
        }

        // S^T = K Q^T
        f32x4v s0 = {0.f, 0.f, 0.f, 0.f}, s1 = {0.f, 0.f, 0.f, 0.f};
        const unsigned short* KlB = &Kl[cur][0];
        __builtin_amdgcn_s_setprio(1);
#pragma unroll
        for (int cc = 0; cc < 8; cc++) {
            s16x8 k0 = *reinterpret_cast<const s16x8*>(KlB + l15 * 256 + ((cc * 32 + lg * 8) ^ swz));
            s16x8 k1 = *reinterpret_cast<const s16x8*>(KlB + (16 + l15) * 256 + ((cc * 32 + lg * 8) ^ swz));
            s0 = __builtin_amdgcn_mfma_f32_16x16x32_bf16(k0, qf[cc], s0, 0, 0, 0);
            s1 = __builtin_amdgcn_mfma_f32_16x16x32_bf16(k1, qf[cc], s1, 0, 0, 0);
        }
        __builtin_amdgcn_s_setprio(0);
#pragma unroll
        for (int jj = 0; jj < 4; jj++) { s0[jj] += mc0[jj]; s1[jj] += mc1[jj]; }
        // reload mask regs for t+1 (drained at next barrier)
        if (t + 1 < 16) {
            mc0 = *reinterpret_cast<const f32x4v*>(mrow + kv0 + 32 + lg * 4);
            mc1 = *reinterpret_cast<const f32x4v*>(mrow + kv0 + 48 + lg * 4);
        }

        // online softmax over kv (in-lane 8 + xor 16/32)
        float pm = fmaxf(fmaxf(fmaxf(s0[0], s0[1]), fmaxf(s0[2], s0[3])),
                         fmaxf(fmaxf(s1[0], s1[1]), fmaxf(s1[2], s1[3])));
        pm = fmaxf(pm, __shfl_xor(pm, 16));
        pm = fmaxf(pm, __shfl_xor(pm, 32));
        if (__any(pm > mrun + 8.f)) {            // defer-max
            float mn = fmaxf(mrun, pm);
            float sc = __expf(mrun - mn);
            mrun = mn;
            lrun *= sc;
#pragma unroll
            for (int ct = 0; ct < 16; ct++)
#pragma unroll
                for (int jj = 0; jj < 4; jj++) oacc[ct][jj] *= sc;
        }
        float p0[4], p1[4];
#pragma unroll
        for (int jj = 0; jj < 4; jj++) {
            p0[jj] = __expf(s0[jj] - mrun);
            p1[jj] = __expf(s1[jj] - mrun);
        }
        float ps = (p0[0] + p0[1]) + (p0[2] + p0[3]) + (p1[0] + p1[1]) + (p1[2] + p1[3]);
        ps += __shfl_xor(ps, 16);
        ps += __shfl_xor(ps, 32);
        lrun += ps;

        // P^T -> Pl (wave-private; compiler inserts lgkmcnt) -> A-fragment
        *reinterpret_cast<ushort4*>(&Pl[wid][l15][lg * 4]) =
            make_ushort4(f2bf(p0[0]), f2bf(p0[1]), f2bf(p0[2]), f2bf(p0[3]));
        *reinterpret_cast<ushort4*>(&Pl[wid][l15][16 + lg * 4]) =
            make_ushort4(f2bf(p1[0]), f2bf(p1[1]), f2bf(p1[2]), f2bf(p1[3]));
        s16x8 pf = *reinterpret_cast<const s16x8*>(&Pl[wid][l15][lg * 8]);

        // O^T += V^T P^T; A-fragment = VlF[ch = ct*16+l15][kv = lg*8..]
        const unsigned short* VlB = &VlF[cur][0];
        __builtin_amdgcn_s_setprio(1);
#pragma unroll
        for (int ct = 0; ct < 16; ct++) {
            s16x8 af = *reinterpret_cast<const s16x8*>(VlB + (ct * 16 + l15) * 32 + lg * 8);
            oacc[ct] = __builtin_amdgcn_mfma_f32_16x16x32_bf16(af, pf, oacc[ct], 0, 0, 0);
        }
        __builtin_amdgcn_s_setprio(0);
    }

    float inv = 1.0f / lrun;
    unsigned short* Op = half ? op1 : op0;
    size_t orow = ((size_t)(b * N_SEQ + q0 + l15)) * (K_HEADS * C_DIM) + kidx * C_DIM + lg * 4;
#pragma unroll
    for (int ct = 0; ct < 16; ct++) {
        *reinterpret_cast<ushort4*>(Op + orow + ct * 16) =
            make_ushort4(f2bf(oacc[ct][0] * inv), f2bf(oacc[ct][1] * inv),
                         f2bf(oacc[ct][2] * inv), f2bf(oacc[ct][3] * inv));
    }
    if (lg == 0)
        mlb[((size_t)(half * 4 + kidx) * 8 + b) * N_SEQ + q0 + l15] = make_float2(mrun, lrun);
}

// ---------------- combine two KV-half partials ----------------
__global__ __launch_bounds__(256) void combine_kernel(const unsigned short* __restrict__ op0,
                                                      const unsigned short* __restrict__ op1,
                                                      const float2* __restrict__ mlb,
                                                      unsigned short* __restrict__ att) {
    int t = blockIdx.x * 256 + threadIdx.x;
    int kidx = (t >> 5) & 3;
    int bn = t >> 7;
    int n = bn & 1023, b = bn >> 10;
    float2 e0 = mlb[((size_t)kidx * 8 + b) * N_SEQ + n];
    float2 e1 = mlb[((size_t)(4 + kidx) * 8 + b) * N_SEQ + n];
    float M = fmaxf(e0.x, e1.x);
    float w0 = e0.y * __expf(e0.x - M);
    float w1 = e1.y * __expf(e1.x - M);
    float r = 1.0f / (w0 + w1);
    w0 *= r;
    w1 *= r;
    s16x8 a = *reinterpret_cast<const s16x8*>(op0 + (size_t)t * 8);
    s16x8 c = *reinterpret_cast<const s16x8*>(op1 + (size_t)t * 8);
    s16x8 o;
#pragma unroll
    for (int i = 0; i < 8; i++)
        o[i] = (short)f2bf(w0 * bf2f((unsigned short)a[i]) + w1 * bf2f((unsigned short)c[i]));
    *reinterpret_cast<s16x8*>(att + (size_t)t * 8) = o;
}

// ---------------- GEMM: C = A(MxK) * Bt(NxK)^T + bias ----------------
template <int BM, int BN, int RELU, int OUTBF>
__global__ __launch_bounds__(256) void gemm_bt_kernel(const unsigned short* __restrict__ A,
                                                      const unsigned short* __restrict__ Bt,
                                                      const float* __restrict__ bias,
                                                      float* __restrict__ Cf,
                                                      unsigned short* __restrict__ Cb,
                                                      int M, int Nn, int Kd) {
    constexpr int WAVES_N = (BM == 128) ? 2 : 4;
    constexpr int WN = BN / WAVES_N;
    constexpr int NT = WN / 16;
    constexpr int TILE = (BM + BN) * 64;
    constexpr int CALLS = (BM + BN) / 32;
    __shared__ unsigned short Sl[2][TILE];
    int tm0 = blockIdx.y * BM, tn0 = blockIdx.x * BN;
    int tid = threadIdx.x, wid = tid >> 6, lane = tid & 63;
    int l15 = lane & 15, lg = lane >> 4;
    int wm = (wid / WAVES_N) * 64, wn = (wid % WAVES_N) * WN;

    f32x4v acc[4][NT];
#pragma unroll
    for (int i = 0; i < 4; i++)
#pragma unroll
        for (int j = 0; j < NT; j++) acc[i][j] = (f32x4v){0.f, 0.f, 0.f, 0.f};

    auto stage = [&](int k0, unsigned short* buf) {
#pragma unroll
        for (int i = 0; i < CALLS; i++) {
            int chb = (i * 4 + wid) * 64;
            int ch = chb + lane;
            const unsigned short* src;
            if (chb < BM * 8) {
                int r = ch >> 3;
                int c8 = ((ch & 7) * 8) ^ ((r & 7) << 3);
                src = A + (size_t)(tm0 + r) * Kd + k0 + c8;
            } else {
                int ch2 = ch - BM * 8;
                int r = ch2 >> 3;
                int c8 = ((ch2 & 7) * 8) ^ ((r & 7) << 3);
                src = Bt + (size_t)(tn0 + r) * Kd + k0 + c8;
            }
            GLOAD_LDS16(src, buf + chb * 8);
        }
    };

    stage(0, &Sl[0][0]);
    int nk = Kd >> 6;
    int swz = (l15 & 7) << 3;
    for (int kt = 0; kt < nk; kt++) {
        int cur = kt & 1;
        __syncthreads();
        if (kt + 1 < nk) stage((kt + 1) * 64, &Sl[cur ^ 1][0]);
        const unsigned short* SA = &Sl[cur][0];
        const unsigned short* SB = SA + BM * 64;
        s16x8 af[4][2], bf[NT][2];
#pragma unroll
        for (int mt = 0; mt < 4; mt++)
#pragma unroll
            for (int h = 0; h < 2; h++)
                af[mt][h] = *reinterpret_cast<const s16x8*>(
                    SA + (wm + mt * 16 + l15) * 64 + ((h * 32 + lg * 8) ^ swz));
#pragma unroll
        for (int nt = 0; nt < NT; nt++)
#pragma unroll
            for (int h = 0; h < 2; h++)
                bf[nt][h] = *reinterpret_cast<const s16x8*>(
                    SB + (wn + nt * 16 + l15) * 64 + ((h * 32 + lg * 8) ^ swz));
        __builtin_amdgcn_s_setprio(1);
#pragma unroll
        for (int mt = 0; mt < 4; mt++)
#pragma unroll
            for (int nt = 0; nt < NT; nt++) {
                acc[mt][nt] = __builtin_amdgcn_mfma_f32_16x16x32_bf16(af[mt][0], bf[nt][0], acc[mt][nt], 0, 0, 0);
                acc[mt][nt] = __builtin_amdgcn_mfma_f32_16x16x32_bf16(af[mt][1], bf[nt][1], acc[mt][nt], 0, 0, 0);
            }
        __builtin_amdgcn_s_setprio(0);
    }

#pragma unroll
    for (int mt = 0; mt < 4; mt++) {
#pragma unroll
        for (int nt = 0; nt < NT; nt++) {
#pragma unroll
            for (int j = 0; j < 4; j++) {
                int row = tm0 + wm + mt * 16 + lg * 4 + j;
                int col = tn0 + wn + nt * 16 + l15;
                float v = acc[mt][nt][j] + bias[col];
                if (RELU) v = fmaxf(v, 0.f);
                if (OUTBF) Cb[(size_t)row * Nn + col] = f2bf(v);
                else       Cf[(size_t)row * Nn + col] = v;
            }
        }
    }
}

// ---------------- fused residual + LayerNorm ----------------
__global__ __launch_bounds__(256) void ln1_kernel(const float* __restrict__ src,
                                                  const float* __restrict__ recT,
                                                  const float* __restrict__ g,
                                                  const float* __restrict__ be,
                                                  float* __restrict__ outf,
                                                  unsigned short* __restrict__ outb) {
    int r = blockIdx.x * 4 + (threadIdx.x >> 6);
    int lane = threadIdx.x & 63;
    int n = r >> 3, b = r & 7;
    int c = lane * 4;
    float4 xs = *reinterpret_cast<const float4*>(src + (size_t)r * C_DIM + c);
    float4 xr = *reinterpret_cast<const float4*>(recT + ((size_t)(b * N_SEQ + n)) * C_DIM + c);
    float x[4] = {xs.x + xr.x, xs.y + xr.y, xs.z + xr.z, xs.w + xr.w};
    float s = x[0] + x[1] + x[2] + x[3];
    float q = x[0] * x[0] + x[1] * x[1] + x[2] * x[2] + x[3] * x[3];
#pragma unroll
    for (int d = 1; d < 64; d <<= 1) {
        s += __shfl_xor(s, d);
        q += __shfl_xor(q, d);
    }
    float mean = s * (1.f / 256.f);
    float var = q * (1.f / 256.f) - mean * mean;
    float rstd = rsqrtf(var + 1e-5f);
    float4 gv = *reinterpret_cast<const float4*>(g + c);
    float4 bv = *reinterpret_cast<const float4*>(be + c);
    float y0 = (x[0] - mean) * rstd * gv.x + bv.x;
    float y1 = (x[1] - mean) * rstd * gv.y + bv.y;
    float y2 = (x[2] - mean) * rstd * gv.z + bv.z;
    float y3 = (x[3] - mean) * rstd * gv.w + bv.w;
    *reinterpret_cast<float4*>(outf + (size_t)r * C_DIM + c) = make_float4(y0, y1, y2, y3);
    *reinterpret_cast<ushort4*>(outb + (size_t)r * C_DIM + c) =
        make_ushort4(f2bf(y0), f2bf(y1), f2bf(y2), f2bf(y3));
}

__global__ __launch_bounds__(256) void ln2_kernel(const float* __restrict__ rec1f,
                                                  const float* __restrict__ ffn,
                                                  const float* __restrict__ g,
                                                  const float* __restrict__ be,
                                                  float* __restrict__ out) {
    int r = blockIdx.x * 4 + (threadIdx.x >> 6);
    int lane = threadIdx.x & 63;
    int c = lane * 4;
    size_t base = (size_t)r * C_DIM + c;
    float4 xa = *reinterpret_cast<const float4*>(rec1f + base);
    float4 xb = *reinterpret_cast<const float4*>(ffn + base);
    float x[4] = {xa.x + xb.x, xa.y + xb.y, xa.z + xb.z, xa.w + xb.w};
    float s = x[0] + x[1] + x[2] + x[3];
    float q = x[0] * x[0] + x[1] * x[1] + x[2] * x[2] + x[3] * x[3];
#pragma unroll
    for (int d = 1; d < 64; d <<= 1) {
        s += __shfl_xor(s, d);
        q += __shfl_xor(q, d);
    }
    float mean = s * (1.f / 256.f);
    float var = q * (1.f / 256.f) - mean * mean;
    float rstd = rsqrtf(var + 1e-5f);
    float4 gv = *reinterpret_cast<const float4*>(g + c);
    float4 bv = *reinterpret_cast<const float4*>(be + c);
    *reinterpret_cast<float4*>(out + base) = make_float4(
        (x[0] - mean) * rstd * gv.x + bv.x,
        (x[1] - mean) * rstd * gv.y + bv.y,
        (x[2] - mean) * rstd * gv.z + bv.z,
        (x[3] - mean) * rstd * gv.w + bv.w);
}

// ---------------- launch ----------------

extern "C" void kernel_launch(void* const* d_in, const int* in_sizes, int n_in,
                              void* d_out, int out_size, void* d_ws, size_t ws_size,
                              hipStream_t stream) {
    const float* src   = (const float*)d_in[0];
    const float* match = (const float*)d_in[1];
    const float* pos   = (const float*)d_in[2];
    const float* mask  = (const float*)d_in[3];
    const float* Wagg  = (const float*)d_in[4];
    const float* bagg  = (const float*)d_in[5];
    const float* W1    = (const float*)d_in[6];
    const float* b1    = (const float*)d_in[7];
    const float* W2    = (const float*)d_in[8];
    const float* b2    = (const float*)d_in[9];
    const float* g1    = (const float*)d_in[10];
    const float* be1   = (const float*)d_in[11];
    const float* g2    = (const float*)d_in[12];
    const float* be2   = (const float*)d_in[13];

    char* ws = (char*)d_ws;
    unsigned short* qb    = (unsigned short*)(ws + 0);          //  4 MB (B,N,C) bf16 pre-scaled
    unsigned short* kb    = (unsigned short*)(ws + 4194304);    // 16 MB (K*B,N,C) bf16
    unsigned short* vfrag = (unsigned short*)(ws + 20971520);   // 16 MB V fragment tiles
    unsigned short* att   = (unsigned short*)(ws + 37748736);   // 16 MB (B,N,K*C) bf16; = op0
    float*          rec_t = (float*)(ws + 57147392);            // 8 MB (B*N,C) f32
    float*          rec1f = (float*)(ws + 65536000);            // 8 MB (N*B,C) f32
    unsigned short* rec1b = (unsigned short*)(ws + 73924608);   // 4 MB bf16
    unsigned short* WaggT = (unsigned short*)(ws + 54525952);   // 0.5 MB
    unsigned short* W1T   = (unsigned short*)(ws + 55050240);   // 1 MB
    unsigned short* W2T   = (unsigned short*)(ws + 56098816);   // 1 MB
    // attention-phase aliases (dead regions during attn):
    unsigned short* op0   = att;                                // 16 MB partial half0
    unsigned short* op1   = (unsigned short*)(ws + 57147392);   // 16 MB partial half1
    float2*         mlb   = (float2*)(ws + 73924608);           // 512 KB (over rec1b)
    unsigned short* hid   = (unsigned short*)(ws + 4194304);    // 32 MB, aliases kb+vfrag
    float*          ffn   = (float*)(ws + 57147392);            // 8 MB, aliases rec_t
    float* outp = (float*)d_out;

    prep_q_kernel<<<2048, 256, 0, stream>>>(src, pos, qb);
    prep_kv_kernel<<<512, 256, 0, stream>>>(match, pos, kb, vfrag);
    transpose_w_kernel<<<1024, 256, 0, stream>>>(Wagg, WaggT, K_HEADS * C_DIM, C_DIM);
    transpose_w_kernel<<<2048, 256, 0, stream>>>(W1, W1T, C_DIM, FF_DIM);
    transpose_w_kernel<<<2048, 256, 0, stream>>>(W2, W2T, FF_DIM, C_DIM);

    attn_kernel<<<512, 512, 0, stream>>>(qb, kb, vfrag, mask, op0, op1, mlb);
    combine_kernel<<<4096, 256, 0, stream>>>(op0, op1, mlb, att);

    gemm_bt_kernel<64, 128, 0, 0><<<dim3(2, 128), 256, 0, stream>>>(
        att, WaggT, bagg, rec_t, nullptr, B_SZ * N_SEQ, C_DIM, K_HEADS * C_DIM);
    ln1_kernel<<<2048, 256, 0, stream>>>(src, rec_t, g1, be1, rec1f, rec1b);
    gemm_bt_kernel<128, 128, 1, 1><<<dim3(16, 64), 256, 0, stream>>>(
        rec1b, W1T, b1, nullptr, hid, N_SEQ * B_SZ, FF_DIM, C_DIM);
    gemm_bt_kernel<64, 128, 0, 0><<<dim3(2, 128), 256, 0, stream>>>(
        hid, W2T, b2, ffn, nullptr, N_SEQ * B_SZ, C_DIM, FF_DIM);
    ln2_kernel<<<2048, 256, 0, stream>>>(rec1f, ffn, g2, be2, outp);
}

// Round 8
// 189.414 us; speedup vs baseline: 1.4774x; 1.1477x over previous
//
#include <hip/hip_runtime.h>

#define N_SEQ 1024
#define B_SZ 8
#define C_DIM 256
#define K_HEADS 4
#define FF_DIM 2048

typedef short s16x8 __attribute__((ext_vector_type(8)));
typedef float f32x4v __attribute__((ext_vector_type(4)));

#define GLOAD_LDS16(src, dst)                                                              \
    __builtin_amdgcn_global_load_lds((const __attribute__((address_space(1))) void*)(src), \
                                     (__attribute__((address_space(3))) void*)(dst), 16, 0, 0)

__device__ __forceinline__ unsigned short f2bf(float f) {
    unsigned u = __builtin_bit_cast(unsigned, f);
    u += 0x7FFFu + ((u >> 16) & 1u);
    return (unsigned short)(u >> 16);
}
__device__ __forceinline__ float bf2f(unsigned short h) {
    unsigned u = ((unsigned)h) << 16;
    return __builtin_bit_cast(float, u);
}

// ---------------- prep kernels ----------------

__global__ __launch_bounds__(256) void prep_q_kernel(const float* __restrict__ src,
                                                     const float* __restrict__ pos,
                                                     unsigned short* __restrict__ qb) {
    int t = blockIdx.x * 256 + threadIdx.x;
    int i4 = t * 4;
    float4 s = *reinterpret_cast<const float4*>(src + i4);
    float4 p = *reinterpret_cast<const float4*>(pos + i4);
    int n = i4 >> 11;
    int rem = i4 & 2047;
    int b = rem >> 8;
    int c = rem & 255;
    int out = (b * N_SEQ + n) * C_DIM + c;
    *reinterpret_cast<ushort4*>(qb + out) = make_ushort4(
        f2bf((s.x + p.x) * 0.0625f), f2bf((s.y + p.y) * 0.0625f),
        f2bf((s.z + p.z) * 0.0625f), f2bf((s.w + p.w) * 0.0625f));
}

// One block per (k,b,ntile of 64): writes kb row-major (+pos) and V in
// per-wave-linear fragment order: vfrag[pr][tile32][ct=16][lane=64][e=8],
// where lane=(lg*16+l15) holds V^T[ch=ct*16+l15][kv=lg*8+e].
__global__ __launch_bounds__(256) void prep_kv_kernel(const float* __restrict__ matched,
                                                      const float* __restrict__ pos,
                                                      unsigned short* __restrict__ kb,
                                                      unsigned short* __restrict__ vfrag) {
    __shared__ unsigned short Vl[64][256];
    int blk = blockIdx.x;
    int nt = blk & 15, pr = blk >> 4;          // pr = k*8+b
    int k = pr >> 3, b = pr & 7;
    int n0 = nt * 64;
    int t = threadIdx.x;
    int c4 = (t & 63) * 4;
#pragma unroll
    for (int r = 0; r < 16; r++) {
        int nl = (t >> 6) * 16 + r;
        int n = n0 + nl;
        size_t mi = ((size_t)(k * N_SEQ + n) * B_SZ + b) * C_DIM + c4;
        float4 m = *reinterpret_cast<const float4*>(matched + mi);
        float4 p = *reinterpret_cast<const float4*>(pos + ((size_t)n * B_SZ + b) * C_DIM + c4);
        *reinterpret_cast<ushort4*>(kb + ((size_t)pr * N_SEQ + n) * C_DIM + c4) =
            make_ushort4(f2bf(m.x + p.x), f2bf(m.y + p.y), f2bf(m.z + p.z), f2bf(m.w + p.w));
        *reinterpret_cast<ushort4*>(&Vl[nl][c4]) =
            make_ushort4(f2bf(m.x), f2bf(m.y), f2bf(m.z), f2bf(m.w));
    }
    __syncthreads();
#pragma unroll
    for (int h = 0; h < 2; h++) {
        unsigned short* tb = vfrag + ((size_t)(pr * 32 + nt * 2 + h)) * 8192;
#pragma unroll
        for (int g = 0; g < 4; g++) {
            int c2 = t + 256 * g;                // chunk index 0..1023
            int ct = c2 >> 6;
            int lane2 = c2 & 63;
            int l152 = lane2 & 15, lg2 = lane2 >> 4;
            s16x8 v;
#pragma unroll
            for (int e = 0; e < 8; e++)
                v[e] = (short)Vl[h * 32 + lg2 * 8 + e][ct * 16 + l152];
            *reinterpret_cast<s16x8*>(tb + (size_t)c2 * 8) = v;
        }
    }
}

__global__ __launch_bounds__(256) void transpose_w_kernel(const float* __restrict__ W,
                                                          unsigned short* __restrict__ Wt,
                                                          int R, int Cn) {
    int idx = blockIdx.x * 256 + threadIdx.x;
    int c = idx / R;
    int r = idx - c * R;
    Wt[idx] = f2bf(W[(size_t)r * Cn + c]);
}

// ---------------- flash attention (KV-split x2, V in registers) ----------------
// grid = 1024 blocks x 256 threads (4 waves x 16 q-rows). K via gload_lds
// double-buffer; V loaded per-iter as coalesced register fragments from vfrag.
__global__ __launch_bounds__(256, 2) void attn_kernel(const unsigned short* __restrict__ qb,
                                                      const unsigned short* __restrict__ kb,
                                                      const unsigned short* __restrict__ vfrag,
                                                      const float* __restrict__ mask,
                                                      unsigned short* __restrict__ op0,
                                                      unsigned short* __restrict__ op1,
                                                      float2* __restrict__ mlb) {
    __shared__ unsigned short Kl[2][8192];       // 32 KB: K tile, XOR-swizzled content
    __shared__ unsigned short Pl[4][16][36];     // 4.6 KB: wave-private P

    int bx = blockIdx.x;
    int b = bx & 7;                              // XCD owns one batch's mask/Q
    int r2 = bx >> 3;
    int half = r2 & 1;
    int kidx = (r2 >> 1) & 3;
    int qt = r2 >> 3;                            // 0..15
    int pr = kidx * 8 + b;

    int tid = threadIdx.x, wid = tid >> 6, lane = tid & 63;
    int l15 = lane & 15, lg = lane >> 4;
    int q0 = qt * 64 + wid * 16;
    int kvh = half * 512;

    // Q fragments
    s16x8 qf[8];
    const unsigned short* qrow = qb + ((size_t)(b * N_SEQ + q0 + l15)) * C_DIM + lg * 8;
#pragma unroll
    for (int cc = 0; cc < 8; cc++) qf[cc] = *reinterpret_cast<const s16x8*>(qrow + cc * 32);

    f32x4v oacc[16];
#pragma unroll
    for (int i = 0; i < 16; i++) oacc[i] = (f32x4v){0.f, 0.f, 0.f, 0.f};
    float mrun = -3e38f, lrun = 0.f;

    const unsigned short* kbp = kb + (size_t)pr * N_SEQ * C_DIM;
    const unsigned short* vfp = vfrag + ((size_t)(pr * 32 + half * 16)) * 8192 + lane * 8;
    const float* mrow = mask + ((size_t)b * N_SEQ + q0 + l15) * N_SEQ + kvh;

    auto stage_k = [&](int kv0, unsigned short* buf) {
#pragma unroll
        for (int i = 0; i < 4; i++) {
            int ch = (wid * 4 + i) * 64 + lane;
            int r = ch >> 5;
            int ce = ((ch & 31) * 8) ^ ((r & 7) << 3);
            GLOAD_LDS16(kbp + (size_t)(kvh + kv0 + r) * C_DIM + ce, &buf[(wid * 4 + i) * 512]);
        }
    };

    // prologue: K tile 0 via gload_lds; mask tile 0 into regs
    stage_k(0, &Kl[0][0]);
    f32x4v mc0 = *reinterpret_cast<const f32x4v*>(mrow + lg * 4);
    f32x4v mc1 = *reinterpret_cast<const f32x4v*>(mrow + 16 + lg * 4);

    int swz = (l15 & 7) << 3;
    for (int t = 0; t < 16; t++) {
        int cur = t & 1;
        int kv0 = t * 32;
        __syncthreads();                         // drains K prefetch; Kl[cur] ready
        if (t + 1 < 16) stage_k(kv0 + 32, &Kl[cur ^ 1][0]);

        // V fragments for THIS tile: 16 coalesced 1KB wave-loads (L2-resident);
        // consumed in PV after QK+softmax -> latency covered.
        const unsigned short* vsrc = vfp + (size_t)t * 8192;
        s16x8 vreg[16];
#pragma unroll
        for (int ct = 0; ct < 16; ct++)
            vreg[ct] = *reinterpret_cast<const s16x8*>(vsrc + ct * 512);

        // S^T = K Q^T
        f32x4v s0 = {0.f, 0.f, 0.f, 0.f}, s1 = {0.f, 0.f, 0.f, 0.f};
        const unsigned short* KlB = &Kl[cur][0];
        __builtin_amdgcn_s_setprio(1);
#pragma unroll
        for (int cc = 0; cc < 8; cc++) {
            s16x8 k0 = *reinterpret_cast<const s16x8*>(KlB + l15 * 256 + ((cc * 32 + lg * 8) ^ swz));
            s16x8 k1 = *reinterpret_cast<const s16x8*>(KlB + (16 + l15) * 256 + ((cc * 32 + lg * 8) ^ swz));
            s0 = __builtin_amdgcn_mfma_f32_16x16x32_bf16(k0, qf[cc], s0, 0, 0, 0);
            s1 = __builtin_amdgcn_mfma_f32_16x16x32_bf16(k1, qf[cc], s1, 0, 0, 0);
        }
        __builtin_amdgcn_s_setprio(0);
#pragma unroll
        for (int jj = 0; jj < 4; jj++) { s0[jj] += mc0[jj]; s1[jj] += mc1[jj]; }
        // reload mask regs for t+1 (drained at next barrier)
        if (t + 1 < 16) {
            mc0 = *reinterpret_cast<const f32x4v*>(mrow + kv0 + 32 + lg * 4);
            mc1 = *reinterpret_cast<const f32x4v*>(mrow + kv0 + 48 + lg * 4);
        }

        // online softmax over kv (in-lane 8 + xor 16/32)
        float pm = fmaxf(fmaxf(fmaxf(s0[0], s0[1]), fmaxf(s0[2], s0[3])),
                         fmaxf(fmaxf(s1[0], s1[1]), fmaxf(s1[2], s1[3])));
        pm = fmaxf(pm, __shfl_xor(pm, 16));
        pm = fmaxf(pm, __shfl_xor(pm, 32));
        if (__any(pm > mrun + 8.f)) {            // defer-max
            float mn = fmaxf(mrun, pm);
            float sc = __expf(mrun - mn);
            mrun = mn;
            lrun *= sc;
#pragma unroll
            for (int ct = 0; ct < 16; ct++)
#pragma unroll
                for (int jj = 0; jj < 4; jj++) oacc[ct][jj] *= sc;
        }
        float p0[4], p1[4];
#pragma unroll
        for (int jj = 0; jj < 4; jj++) {
            p0[jj] = __expf(s0[jj] - mrun);
            p1[jj] = __expf(s1[jj] - mrun);
        }
        float ps = (p0[0] + p0[1]) + (p0[2] + p0[3]) + (p1[0] + p1[1]) + (p1[2] + p1[3]);
        ps += __shfl_xor(ps, 16);
        ps += __shfl_xor(ps, 32);
        lrun += ps;

        // P^T -> Pl (wave-private; compiler inserts lgkmcnt) -> A-fragment
        *reinterpret_cast<ushort4*>(&Pl[wid][l15][lg * 4]) =
            make_ushort4(f2bf(p0[0]), f2bf(p0[1]), f2bf(p0[2]), f2bf(p0[3]));
        *reinterpret_cast<ushort4*>(&Pl[wid][l15][16 + lg * 4]) =
            make_ushort4(f2bf(p1[0]), f2bf(p1[1]), f2bf(p1[2]), f2bf(p1[3]));
        s16x8 pf = *reinterpret_cast<const s16x8*>(&Pl[wid][l15][lg * 8]);

        // O^T += V^T P^T — pure-register MFMA chain
        __builtin_amdgcn_s_setprio(1);
#pragma unroll
        for (int ct = 0; ct < 16; ct++)
            oacc[ct] = __builtin_amdgcn_mfma_f32_16x16x32_bf16(vreg[ct], pf, oacc[ct], 0, 0, 0);
        __builtin_amdgcn_s_setprio(0);
    }

    float inv = 1.0f / lrun;
    unsigned short* Op = half ? op1 : op0;
    size_t orow = ((size_t)(b * N_SEQ + q0 + l15)) * (K_HEADS * C_DIM) + kidx * C_DIM + lg * 4;
#pragma unroll
    for (int ct = 0; ct < 16; ct++) {
        *reinterpret_cast<ushort4*>(Op + orow + ct * 16) =
            make_ushort4(f2bf(oacc[ct][0] * inv), f2bf(oacc[ct][1] * inv),
                         f2bf(oacc[ct][2] * inv), f2bf(oacc[ct][3] * inv));
    }
    if (lg == 0)
        mlb[((size_t)(half * 4 + kidx) * 8 + b) * N_SEQ + q0 + l15] = make_float2(mrun, lrun);
}

// ---------------- combine two KV-half partials ----------------
__global__ __launch_bounds__(256) void combine_kernel(const unsigned short* __restrict__ op0,
                                                      const unsigned short* __restrict__ op1,
                                                      const float2* __restrict__ mlb,
                                                      unsigned short* __restrict__ att) {
    int t = blockIdx.x * 256 + threadIdx.x;
    int kidx = (t >> 5) & 3;
    int bn = t >> 7;
    int n = bn & 1023, b = bn >> 10;
    float2 e0 = mlb[((size_t)kidx * 8 + b) * N_SEQ + n];
    float2 e1 = mlb[((size_t)(4 + kidx) * 8 + b) * N_SEQ + n];
    float M = fmaxf(e0.x, e1.x);
    float w0 = e0.y * __expf(e0.x - M);
    float w1 = e1.y * __expf(e1.x - M);
    float r = 1.0f / (w0 + w1);
    w0 *= r;
    w1 *= r;
    s16x8 a = *reinterpret_cast<const s16x8*>(op0 + (size_t)t * 8);
    s16x8 c = *reinterpret_cast<const s16x8*>(op1 + (size_t)t * 8);
    s16x8 o;
#pragma unroll
    for (int i = 0; i < 8; i++)
        o[i] = (short)f2bf(w0 * bf2f((unsigned short)a[i]) + w1 * bf2f((unsigned short)c[i]));
    *reinterpret_cast<s16x8*>(att + (size_t)t * 8) = o;
}

// ---------------- GEMM: C = A(MxK) * Bt(NxK)^T + bias ----------------
template <int BM, int BN, int RELU, int OUTBF>
__global__ __launch_bounds__(256) void gemm_bt_kernel(const unsigned short* __restrict__ A,
                                                      const unsigned short* __restrict__ Bt,
                                                      const float* __restrict__ bias,
                                                      float* __restrict__ Cf,
                                                      unsigned short* __restrict__ Cb,
                                                      int M, int Nn, int Kd) {
    constexpr int WAVES_N = (BM == 128) ? 2 : 4;
    constexpr int WN = BN / WAVES_N;
    constexpr int NT = WN / 16;
    constexpr int TILE = (BM + BN) * 64;
    constexpr int CALLS = (BM + BN) / 32;
    __shared__ unsigned short Sl[2][TILE];
    int tm0 = blockIdx.y * BM, tn0 = blockIdx.x * BN;
    int tid = threadIdx.x, wid = tid >> 6, lane = tid & 63;
    int l15 = lane & 15, lg = lane >> 4;
    int wm = (wid / WAVES_N) * 64, wn = (wid % WAVES_N) * WN;

    f32x4v acc[4][NT];
#pragma unroll
    for (int i = 0; i < 4; i++)
#pragma unroll
        for (int j = 0; j < NT; j++) acc[i][j] = (f32x4v){0.f, 0.f, 0.f, 0.f};

    auto stage = [&](int k0, unsigned short* buf) {
#pragma unroll
        for (int i = 0; i < CALLS; i++) {
            int chb = (i * 4 + wid) * 64;
            int ch = chb + lane;
            const unsigned short* src;
            if (chb < BM * 8) {
                int r = ch >> 3;
                int c8 = ((ch & 7) * 8) ^ ((r & 7) << 3);
                src = A + (size_t)(tm0 + r) * Kd + k0 + c8;
            } else {
                int ch2 = ch - BM * 8;
                int r = ch2 >> 3;
                int c8 = ((ch2 & 7) * 8) ^ ((r & 7) << 3);
                src = Bt + (size_t)(tn0 + r) * Kd + k0 + c8;
            }
            GLOAD_LDS16(src, buf + chb * 8);
        }
    };

    stage(0, &Sl[0][0]);
    int nk = Kd >> 6;
    int swz = (l15 & 7) << 3;
    for (int kt = 0; kt < nk; kt++) {
        int cur = kt & 1;
        __syncthreads();
        if (kt + 1 < nk) stage((kt + 1) * 64, &Sl[cur ^ 1][0]);
        const unsigned short* SA = &Sl[cur][0];
        const unsigned short* SB = SA + BM * 64;
        s16x8 af[4][2], bf[NT][2];
#pragma unroll
        for (int mt = 0; mt < 4; mt++)
#pragma unroll
            for (int h = 0; h < 2; h++)
                af[mt][h] = *reinterpret_cast<const s16x8*>(
                    SA + (wm + mt * 16 + l15) * 64 + ((h * 32 + lg * 8) ^ swz));
#pragma unroll
        for (int nt = 0; nt < NT; nt++)
#pragma unroll
            for (int h = 0; h < 2; h++)
                bf[nt][h] = *reinterpret_cast<const s16x8*>(
                    SB + (wn + nt * 16 + l15) * 64 + ((h * 32 + lg * 8) ^ swz));
        __builtin_amdgcn_s_setprio(1);
#pragma unroll
        for (int mt = 0; mt < 4; mt++)
#pragma unroll
            for (int nt = 0; nt < NT; nt++) {
                acc[mt][nt] = __builtin_amdgcn_mfma_f32_16x16x32_bf16(af[mt][0], bf[nt][0], acc[mt][nt], 0, 0, 0);
                acc[mt][nt] = __builtin_amdgcn_mfma_f32_16x16x32_bf16(af[mt][1], bf[nt][1], acc[mt][nt], 0, 0, 0);
            }
        __builtin_amdgcn_s_setprio(0);
    }

#pragma unroll
    for (int mt = 0; mt < 4; mt++) {
#pragma unroll
        for (int nt = 0; nt < NT; nt++) {
#pragma unroll
            for (int j = 0; j < 4; j++) {
                int row = tm0 + wm + mt * 16 + lg * 4 + j;
                int col = tn0 + wn + nt * 16 + l15;
                float v = acc[mt][nt][j] + bias[col];
                if (RELU) v = fmaxf(v, 0.f);
                if (OUTBF) Cb[(size_t)row * Nn + col] = f2bf(v);
                else       Cf[(size_t)row * Nn + col] = v;
            }
        }
    }
}

// ---------------- fused residual + LayerNorm ----------------
__global__ __launch_bounds__(256) void ln1_kernel(const float* __restrict__ src,
                                                  const float* __restrict__ recT,
                                                  const float* __restrict__ g,
                                                  const float* __restrict__ be,
                                                  float* __restrict__ outf,
                                                  unsigned short* __restrict__ outb) {
    int r = blockIdx.x * 4 + (threadIdx.x >> 6);
    int lane = threadIdx.x & 63;
    int n = r >> 3, b = r & 7;
    int c = lane * 4;
    float4 xs = *reinterpret_cast<const float4*>(src + (size_t)r * C_DIM + c);
    float4 xr = *reinterpret_cast<const float4*>(recT + ((size_t)(b * N_SEQ + n)) * C_DIM + c);
    float x[4] = {xs.x + xr.x, xs.y + xr.y, xs.z + xr.z, xs.w + xr.w};
    float s = x[0] + x[1] + x[2] + x[3];
    float q = x[0] * x[0] + x[1] * x[1] + x[2] * x[2] + x[3] * x[3];
#pragma unroll
    for (int d = 1; d < 64; d <<= 1) {
        s += __shfl_xor(s, d);
        q += __shfl_xor(q, d);
    }
    float mean = s * (1.f / 256.f);
    float var = q * (1.f / 256.f) - mean * mean;
    float rstd = rsqrtf(var + 1e-5f);
    float4 gv = *reinterpret_cast<const float4*>(g + c);
    float4 bv = *reinterpret_cast<const float4*>(be + c);
    float y0 = (x[0] - mean) * rstd * gv.x + bv.x;
    float y1 = (x[1] - mean) * rstd * gv.y + bv.y;
    float y2 = (x[2] - mean) * rstd * gv.z + bv.z;
    float y3 = (x[3] - mean) * rstd * gv.w + bv.w;
    *reinterpret_cast<float4*>(outf + (size_t)r * C_DIM + c) = make_float4(y0, y1, y2, y3);
    *reinterpret_cast<ushort4*>(outb + (size_t)r * C_DIM + c) =
        make_ushort4(f2bf(y0), f2bf(y1), f2bf(y2), f2bf(y3));
}

__global__ __launch_bounds__(256) void ln2_kernel(const float* __restrict__ rec1f,
                                                  const float* __restrict__ ffn,
                                                  const float* __restrict__ g,
                                                  const float* __restrict__ be,
                                                  float* __restrict__ out) {
    int r = blockIdx.x * 4 + (threadIdx.x >> 6);
    int lane = threadIdx.x & 63;
    int c = lane * 4;
    size_t base = (size_t)r * C_DIM + c;
    float4 xa = *reinterpret_cast<const float4*>(rec1f + base);
    float4 xb = *reinterpret_cast<const float4*>(ffn + base);
    float x[4] = {xa.x + xb.x, xa.y + xb.y, xa.z + xb.z, xa.w + xb.w};
    float s = x[0] + x[1] + x[2] + x[3];
    float q = x[0] * x[0] + x[1] * x[1] + x[2] * x[2] + x[3] * x[3];
#pragma unroll
    for (int d = 1; d < 64; d <<= 1) {
        s += __shfl_xor(s, d);
        q += __shfl_xor(q, d);
    }
    float mean = s * (1.f / 256.f);
    float var = q * (1.f / 256.f) - mean * mean;
    float rstd = rsqrtf(var + 1e-5f);
    float4 gv = *reinterpret_cast<const float4*>(g + c);
    float4 bv = *reinterpret_cast<const float4*>(be + c);
    *reinterpret_cast<float4*>(out + base) = make_float4(
        (x[0] - mean) * rstd * gv.x + bv.x,
        (x[1] - mean) * rstd * gv.y + bv.y,
        (x[2] - mean) * rstd * gv.z + bv.z,
        (x[3] - mean) * rstd * gv.w + bv.w);
}

// ---------------- launch ----------------

extern "C" void kernel_launch(void* const* d_in, const int* in_sizes, int n_in,
                              void* d_out, int out_size, void* d_ws, size_t ws_size,
                              hipStream_t stream) {
    const float* src   = (const float*)d_in[0];
    const float* match = (const float*)d_in[1];
    const float* pos   = (const float*)d_in[2];
    const float* mask  = (const float*)d_in[3];
    const float* Wagg  = (const float*)d_in[4];
    const float* bagg  = (const float*)d_in[5];
    const float* W1    = (const float*)d_in[6];
    const float* b1    = (const float*)d_in[7];
    const float* W2    = (const float*)d_in[8];
    const float* b2    = (const float*)d_in[9];
    const float* g1    = (const float*)d_in[10];
    const float* be1   = (const float*)d_in[11];
    const float* g2    = (const float*)d_in[12];
    const float* be2   = (const float*)d_in[13];

    char* ws = (char*)d_ws;
    unsigned short* qb    = (unsigned short*)(ws + 0);          //  4 MB (B,N,C) bf16 pre-scaled
    unsigned short* kb    = (unsigned short*)(ws + 4194304);    // 16 MB (K*B,N,C) bf16
    unsigned short* vfrag = (unsigned short*)(ws + 20971520);   // 16 MB V fragment tiles
    unsigned short* att   = (unsigned short*)(ws + 37748736);   // 16 MB (B,N,K*C) bf16; = op0
    float*          rec_t = (float*)(ws + 57147392);            // 8 MB (B*N,C) f32
    float*          rec1f = (float*)(ws + 65536000);            // 8 MB (N*B,C) f32
    unsigned short* rec1b = (unsigned short*)(ws + 73924608);   // 4 MB bf16
    unsigned short* WaggT = (unsigned short*)(ws + 54525952);   // 0.5 MB
    unsigned short* W1T   = (unsigned short*)(ws + 55050240);   // 1 MB
    unsigned short* W2T   = (unsigned short*)(ws + 56098816);   // 1 MB
    // attention-phase aliases (dead regions during attn):
    unsigned short* op0   = att;                                // 16 MB partial half0
    unsigned short* op1   = (unsigned short*)(ws + 57147392);   // 16 MB partial half1
    float2*         mlb   = (float2*)(ws + 73924608);           // 512 KB (over rec1b)
    unsigned short* hid   = (unsigned short*)(ws + 4194304);    // 32 MB, aliases kb+vfrag
    float*          ffn   = (float*)(ws + 57147392);            // 8 MB, aliases rec_t
    float* outp = (float*)d_out;

    prep_q_kernel<<<2048, 256, 0, stream>>>(src, pos, qb);
    prep_kv_kernel<<<512, 256, 0, stream>>>(match, pos, kb, vfrag);
    transpose_w_kernel<<<1024, 256, 0, stream>>>(Wagg, WaggT, K_HEADS * C_DIM, C_DIM);
    transpose_w_kernel<<<2048, 256, 0, stream>>>(W1, W1T, C_DIM, FF_DIM);
    transpose_w_kernel<<<2048, 256, 0, stream>>>(W2, W2T, FF_DIM, C_DIM);

    attn_kernel<<<1024, 256, 0, stream>>>(qb, kb, vfrag, mask, op0, op1, mlb);
    combine_kernel<<<4096, 256, 0, stream>>>(op0, op1, mlb, att);

    gemm_bt_kernel<64, 128, 0, 0><<<dim3(2, 128), 256, 0, stream>>>(
        att, WaggT, bagg, rec_t, nullptr, B_SZ * N_SEQ, C_DIM, K_HEADS * C_DIM);
    ln1_kernel<<<2048, 256, 0, stream>>>(src, rec_t, g1, be1, rec1f, rec1b);
    gemm_bt_kernel<128, 128, 1, 1><<<dim3(16, 64), 256, 0, stream>>>(
        rec1b, W1T, b1, nullptr, hid, N_SEQ * B_SZ, FF_DIM, C_DIM);
    gemm_bt_kernel<64, 128, 0, 0><<<dim3(2, 128), 256, 0, stream>>>(
        hid, W2T, b2, ffn, nullptr, N_SEQ * B_SZ, C_DIM, FF_DIM);
    ln2_kernel<<<2048, 256, 0, stream>>>(rec1f, ffn, g2, be2, outp);
}

// Round 9
// 159.580 us; speedup vs baseline: 1.7536x; 1.1870x over previous
//
#include <hip/hip_runtime.h>

#define N_SEQ 1024
#define B_SZ 8
#define C_DIM 256
#define K_HEADS 4
#define FF_DIM 2048

typedef short s16x8 __attribute__((ext_vector_type(8)));
typedef float f32x4v __attribute__((ext_vector_type(4)));

#define GLOAD_LDS16(src, dst)                                                              \
    __builtin_amdgcn_global_load_lds((const __attribute__((address_space(1))) void*)(src), \
                                     (__attribute__((address_space(3))) void*)(dst), 16, 0, 0)

__device__ __forceinline__ unsigned short f2bf(float f) {
    unsigned u = __builtin_bit_cast(unsigned, f);
    u += 0x7FFFu + ((u >> 16) & 1u);
    return (unsigned short)(u >> 16);
}

// ---------------- prep kernels ----------------

__global__ __launch_bounds__(256) void prep_q_kernel(const float* __restrict__ src,
                                                     const float* __restrict__ pos,
                                                     unsigned short* __restrict__ qb) {
    int t = blockIdx.x * 256 + threadIdx.x;
    int i4 = t * 4;
    float4 s = *reinterpret_cast<const float4*>(src + i4);
    float4 p = *reinterpret_cast<const float4*>(pos + i4);
    int n = i4 >> 11;
    int rem = i4 & 2047;
    int b = rem >> 8;
    int c = rem & 255;
    int out = (b * N_SEQ + n) * C_DIM + c;
    *reinterpret_cast<ushort4*>(qb + out) = make_ushort4(
        f2bf((s.x + p.x) * 0.0625f), f2bf((s.y + p.y) * 0.0625f),
        f2bf((s.z + p.z) * 0.0625f), f2bf((s.w + p.w) * 0.0625f));
}

// One block per (k,b,ntile of 64): writes kb row-major (+pos) and V in
// per-wave-linear fragment order: vfrag[pr][tile32][ct=16][lane=64][e=8],
// where lane=(lg*16+l15) holds V^T[ch=ct*16+l15][kv=lg*8+e].
__global__ __launch_bounds__(256) void prep_kv_kernel(const float* __restrict__ matched,
                                                      const float* __restrict__ pos,
                                                      unsigned short* __restrict__ kb,
                                                      unsigned short* __restrict__ vfrag) {
    __shared__ unsigned short Vl[64][256];
    int blk = blockIdx.x;
    int nt = blk & 15, pr = blk >> 4;          // pr = k*8+b
    int k = pr >> 3, b = pr & 7;
    int n0 = nt * 64;
    int t = threadIdx.x;
    int c4 = (t & 63) * 4;
#pragma unroll
    for (int r = 0; r < 16; r++) {
        int nl = (t >> 6) * 16 + r;
        int n = n0 + nl;
        size_t mi = ((size_t)(k * N_SEQ + n) * B_SZ + b) * C_DIM + c4;
        float4 m = *reinterpret_cast<const float4*>(matched + mi);
        float4 p = *reinterpret_cast<const float4*>(pos + ((size_t)n * B_SZ + b) * C_DIM + c4);
        *reinterpret_cast<ushort4*>(kb + ((size_t)pr * N_SEQ + n) * C_DIM + c4) =
            make_ushort4(f2bf(m.x + p.x), f2bf(m.y + p.y), f2bf(m.z + p.z), f2bf(m.w + p.w));
        *reinterpret_cast<ushort4*>(&Vl[nl][c4]) =
            make_ushort4(f2bf(m.x), f2bf(m.y), f2bf(m.z), f2bf(m.w));
    }
    __syncthreads();
#pragma unroll
    for (int h = 0; h < 2; h++) {
        unsigned short* tb = vfrag + ((size_t)(pr * 32 + nt * 2 + h)) * 8192;
#pragma unroll
        for (int g = 0; g < 4; g++) {
            int c2 = t + 256 * g;                // chunk index 0..1023
            int ct = c2 >> 6;
            int lane2 = c2 & 63;
            int l152 = lane2 & 15, lg2 = lane2 >> 4;
            s16x8 v;
#pragma unroll
            for (int e = 0; e < 8; e++)
                v[e] = (short)Vl[h * 32 + lg2 * 8 + e][ct * 16 + l152];
            *reinterpret_cast<s16x8*>(tb + (size_t)c2 * 8) = v;
        }
    }
}

__global__ __launch_bounds__(256) void transpose_w_kernel(const float* __restrict__ W,
                                                          unsigned short* __restrict__ Wt,
                                                          int R, int Cn) {
    int idx = blockIdx.x * 256 + threadIdx.x;
    int c = idx / R;
    int r = idx - c * R;
    Wt[idx] = f2bf(W[(size_t)r * Cn + c]);
}

// ---------------- flash attention (single-pass, cooperative ch-split PV) ----------------
// grid = 512 blocks x 256 threads. Block = 64 q (4 waves). Wave w: QK+softmax for
// q-tile w; PV for channel quarter [w*64, w*64+64) of ALL 4 q-tiles (P via LDS).
__global__ __launch_bounds__(256, 2) void attn_kernel(const unsigned short* __restrict__ qb,
                                                      const unsigned short* __restrict__ kb,
                                                      const unsigned short* __restrict__ vfrag,
                                                      const float* __restrict__ mask,
                                                      unsigned short* __restrict__ att) {
    __shared__ unsigned short Kl[2][8192];       // 32 KB: K tile, XOR-swizzled content
    __shared__ unsigned short Psh[2][4][16][40]; // 10 KB: P exchange, dbuf
    __shared__ float scl[2][4][17];              // rescale factors, dbuf
    __shared__ float lrex[4][17];                // final l exchange

    int bx = blockIdx.x;
    int b = bx & 7;                              // XCD owns one batch's mask/Q
    int r2 = bx >> 3;
    int kidx = r2 & 3;
    int qtb = r2 >> 2;                           // 0..15 (64-q tiles)
    int pr = kidx * 8 + b;

    int tid = threadIdx.x, wid = tid >> 6, lane = tid & 63;
    int l15 = lane & 15, lg = lane >> 4;
    int q0 = qtb * 64 + wid * 16;                // wave's own q-tile base

    // Q fragments (wave's own 16 q)
    s16x8 qf[8];
    const unsigned short* qrow = qb + ((size_t)(b * N_SEQ + q0 + l15)) * C_DIM + lg * 8;
#pragma unroll
    for (int cc = 0; cc < 8; cc++) qf[cc] = *reinterpret_cast<const s16x8*>(qrow + cc * 32);

    // O^T accumulator: oacc[j*4+c] = O^T[ch = wid*64 + c*16 + (lg*4+jj)][q-tile j, col l15]
    f32x4v oacc[16];
#pragma unroll
    for (int i = 0; i < 16; i++) oacc[i] = (f32x4v){0.f, 0.f, 0.f, 0.f};
    float mrun = -3e38f, lrun = 0.f;

    const unsigned short* kbp = kb + (size_t)pr * N_SEQ * C_DIM;
    const unsigned short* vfp = vfrag + (size_t)pr * 32 * 8192 + lane * 8;
    const float* mrow = mask + ((size_t)b * N_SEQ + q0 + l15) * N_SEQ;

    auto stage_k = [&](int kv0, unsigned short* buf) {
#pragma unroll
        for (int i = 0; i < 4; i++) {
            int ch = (wid * 4 + i) * 64 + lane;
            int r = ch >> 5;
            int ce = ((ch & 31) * 8) ^ ((r & 7) << 3);
            GLOAD_LDS16(kbp + (size_t)(kv0 + r) * C_DIM + ce, &buf[(wid * 4 + i) * 512]);
        }
    };

    // prologue
    stage_k(0, &Kl[0][0]);
    f32x4v mc0 = *reinterpret_cast<const f32x4v*>(mrow + lg * 4);
    f32x4v mc1 = *reinterpret_cast<const f32x4v*>(mrow + 16 + lg * 4);

    int swz = (l15 & 7) << 3;
    for (int t = 0; t < 32; t++) {
        int cur = t & 1;
        int kv0 = t * 32;
        __syncthreads();                         // (A) K[t] ready; Psh[cur] free
        if (t + 1 < 32) stage_k(kv0 + 32, &Kl[cur ^ 1][0]);

        // V fragments for this wave's channel quarter (4 coalesced 1KB loads, L2)
        const unsigned short* vsrc = vfp + (size_t)t * 8192;
        s16x8 vreg[4];
#pragma unroll
        for (int c = 0; c < 4; c++)
            vreg[c] = *reinterpret_cast<const s16x8*>(vsrc + (wid * 4 + c) * 512);

        // S^T = K Q^T (own q-tile)
        f32x4v s0 = {0.f, 0.f, 0.f, 0.f}, s1 = {0.f, 0.f, 0.f, 0.f};
        const unsigned short* KlB = &Kl[cur][0];
        __builtin_amdgcn_s_setprio(1);
#pragma unroll
        for (int cc = 0; cc < 8; cc++) {
            s16x8 k0 = *reinterpret_cast<const s16x8*>(KlB + l15 * 256 + ((cc * 32 + lg * 8) ^ swz));
            s16x8 k1 = *reinterpret_cast<const s16x8*>(KlB + (16 + l15) * 256 + ((cc * 32 + lg * 8) ^ swz));
            s0 = __builtin_amdgcn_mfma_f32_16x16x32_bf16(k0, qf[cc], s0, 0, 0, 0);
            s1 = __builtin_amdgcn_mfma_f32_16x16x32_bf16(k1, qf[cc], s1, 0, 0, 0);
        }
        __builtin_amdgcn_s_setprio(0);
#pragma unroll
        for (int jj = 0; jj < 4; jj++) { s0[jj] += mc0[jj]; s1[jj] += mc1[jj]; }
        if (t + 1 < 32) {
            mc0 = *reinterpret_cast<const f32x4v*>(mrow + kv0 + 32 + lg * 4);
            mc1 = *reinterpret_cast<const f32x4v*>(mrow + kv0 + 48 + lg * 4);
        }

        // online softmax over kv (in-lane 8 + xor 16/32)
        float pm = fmaxf(fmaxf(fmaxf(s0[0], s0[1]), fmaxf(s0[2], s0[3])),
                         fmaxf(fmaxf(s1[0], s1[1]), fmaxf(s1[2], s1[3])));
        pm = fmaxf(pm, __shfl_xor(pm, 16));
        pm = fmaxf(pm, __shfl_xor(pm, 32));
        float sc = 1.0f;
        if (__any(pm > mrun + 8.f)) {            // defer-max
            float mn = fmaxf(mrun, pm);
            sc = __expf(mrun - mn);
            mrun = mn;
        }
        float p0[4], p1[4];
#pragma unroll
        for (int jj = 0; jj < 4; jj++) {
            p0[jj] = __expf(s0[jj] - mrun);
            p1[jj] = __expf(s1[jj] - mrun);
        }
        float ps = (p0[0] + p0[1]) + (p0[2] + p0[3]) + (p1[0] + p1[1]) + (p1[2] + p1[3]);
        ps += __shfl_xor(ps, 16);
        ps += __shfl_xor(ps, 32);
        lrun = lrun * sc + ps;

        // publish P (A-fragment layout) + rescale factor
        *reinterpret_cast<ushort4*>(&Psh[cur][wid][l15][lg * 4]) =
            make_ushort4(f2bf(p0[0]), f2bf(p0[1]), f2bf(p0[2]), f2bf(p0[3]));
        *reinterpret_cast<ushort4*>(&Psh[cur][wid][l15][16 + lg * 4]) =
            make_ushort4(f2bf(p1[0]), f2bf(p1[1]), f2bf(p1[2]), f2bf(p1[3]));
        if (lane < 16) scl[cur][wid][lane] = sc;
        __syncthreads();                         // (B) P + sc visible

        // PV: this wave's 64 channels x all 4 q-tiles
        __builtin_amdgcn_s_setprio(1);
#pragma unroll
        for (int j = 0; j < 4; j++) {
            float scj = scl[cur][j][l15];
            s16x8 pf = *reinterpret_cast<const s16x8*>(&Psh[cur][j][l15][lg * 8]);
#pragma unroll
            for (int c = 0; c < 4; c++) {
                int idx = j * 4 + c;
#pragma unroll
                for (int jj = 0; jj < 4; jj++) oacc[idx][jj] *= scj;
                oacc[idx] = __builtin_amdgcn_mfma_f32_16x16x32_bf16(vreg[c], pf, oacc[idx], 0, 0, 0);
            }
        }
        __builtin_amdgcn_s_setprio(0);
    }

    // epilogue: exchange l, normalize, write O
    if (lane < 16) lrex[wid][lane] = lrun;
    __syncthreads();
#pragma unroll
    for (int j = 0; j < 4; j++) {
        float invj = 1.0f / lrex[j][l15];
#pragma unroll
        for (int c = 0; c < 4; c++) {
            int idx = j * 4 + c;
            size_t orow = ((size_t)(b * N_SEQ + qtb * 64 + j * 16 + l15)) * (K_HEADS * C_DIM)
                          + kidx * C_DIM + wid * 64 + c * 16 + lg * 4;
            *reinterpret_cast<ushort4*>(att + orow) =
                make_ushort4(f2bf(oacc[idx][0] * invj), f2bf(oacc[idx][1] * invj),
                             f2bf(oacc[idx][2] * invj), f2bf(oacc[idx][3] * invj));
        }
    }
}

// ---------------- GEMM: C = A(MxK) * Bt(NxK)^T + bias ----------------
template <int BM, int BN, int RELU, int OUTBF>
__global__ __launch_bounds__(256) void gemm_bt_kernel(const unsigned short* __restrict__ A,
                                                      const unsigned short* __restrict__ Bt,
                                                      const float* __restrict__ bias,
                                                      float* __restrict__ Cf,
                                                      unsigned short* __restrict__ Cb,
                                                      int M, int Nn, int Kd) {
    constexpr int WAVES_N = (BM == 128) ? 2 : 4;
    constexpr int WN = BN / WAVES_N;
    constexpr int NT = WN / 16;
    constexpr int TILE = (BM + BN) * 64;
    constexpr int CALLS = (BM + BN) / 32;
    __shared__ unsigned short Sl[2][TILE];
    int tm0 = blockIdx.y * BM, tn0 = blockIdx.x * BN;
    int tid = threadIdx.x, wid = tid >> 6, lane = tid & 63;
    int l15 = lane & 15, lg = lane >> 4;
    int wm = (wid / WAVES_N) * 64, wn = (wid % WAVES_N) * WN;

    f32x4v acc[4][NT];
#pragma unroll
    for (int i = 0; i < 4; i++)
#pragma unroll
        for (int j = 0; j < NT; j++) acc[i][j] = (f32x4v){0.f, 0.f, 0.f, 0.f};

    auto stage = [&](int k0, unsigned short* buf) {
#pragma unroll
        for (int i = 0; i < CALLS; i++) {
            int chb = (i * 4 + wid) * 64;
            int ch = chb + lane;
            const unsigned short* src;
            if (chb < BM * 8) {
                int r = ch >> 3;
                int c8 = ((ch & 7) * 8) ^ ((r & 7) << 3);
                src = A + (size_t)(tm0 + r) * Kd + k0 + c8;
            } else {
                int ch2 = ch - BM * 8;
                int r = ch2 >> 3;
                int c8 = ((ch2 & 7) * 8) ^ ((r & 7) << 3);
                src = Bt + (size_t)(tn0 + r) * Kd + k0 + c8;
            }
            GLOAD_LDS16(src, buf + chb * 8);
        }
    };

    stage(0, &Sl[0][0]);
    int nk = Kd >> 6;
    int swz = (l15 & 7) << 3;
    for (int kt = 0; kt < nk; kt++) {
        int cur = kt & 1;
        __syncthreads();
        if (kt + 1 < nk) stage((kt + 1) * 64, &Sl[cur ^ 1][0]);
        const unsigned short* SA = &Sl[cur][0];
        const unsigned short* SB = SA + BM * 64;
        s16x8 af[4][2], bf[NT][2];
#pragma unroll
        for (int mt = 0; mt < 4; mt++)
#pragma unroll
            for (int h = 0; h < 2; h++)
                af[mt][h] = *reinterpret_cast<const s16x8*>(
                    SA + (wm + mt * 16 + l15) * 64 + ((h * 32 + lg * 8) ^ swz));
#pragma unroll
        for (int nt = 0; nt < NT; nt++)
#pragma unroll
            for (int h = 0; h < 2; h++)
                bf[nt][h] = *reinterpret_cast<const s16x8*>(
                    SB + (wn + nt * 16 + l15) * 64 + ((h * 32 + lg * 8) ^ swz));
        __builtin_amdgcn_s_setprio(1);
#pragma unroll
        for (int mt = 0; mt < 4; mt++)
#pragma unroll
            for (int nt = 0; nt < NT; nt++) {
                acc[mt][nt] = __builtin_amdgcn_mfma_f32_16x16x32_bf16(af[mt][0], bf[nt][0], acc[mt][nt], 0, 0, 0);
                acc[mt][nt] = __builtin_amdgcn_mfma_f32_16x16x32_bf16(af[mt][1], bf[nt][1], acc[mt][nt], 0, 0, 0);
            }
        __builtin_amdgcn_s_setprio(0);
    }

#pragma unroll
    for (int mt = 0; mt < 4; mt++) {
#pragma unroll
        for (int nt = 0; nt < NT; nt++) {
#pragma unroll
            for (int j = 0; j < 4; j++) {
                int row = tm0 + wm + mt * 16 + lg * 4 + j;
                int col = tn0 + wn + nt * 16 + l15;
                float v = acc[mt][nt][j] + bias[col];
                if (RELU) v = fmaxf(v, 0.f);
                if (OUTBF) Cb[(size_t)row * Nn + col] = f2bf(v);
                else       Cf[(size_t)row * Nn + col] = v;
            }
        }
    }
}

// ---------------- fused residual + LayerNorm ----------------
__global__ __launch_bounds__(256) void ln1_kernel(const float* __restrict__ src,
                                                  const float* __restrict__ recT,
                                                  const float* __restrict__ g,
                                                  const float* __restrict__ be,
                                                  float* __restrict__ outf,
                                                  unsigned short* __restrict__ outb) {
    int r = blockIdx.x * 4 + (threadIdx.x >> 6);
    int lane = threadIdx.x & 63;
    int n = r >> 3, b = r & 7;
    int c = lane * 4;
    float4 xs = *reinterpret_cast<const float4*>(src + (size_t)r * C_DIM + c);
    float4 xr = *reinterpret_cast<const float4*>(recT + ((size_t)(b * N_SEQ + n)) * C_DIM + c);
    float x[4] = {xs.x + xr.x, xs.y + xr.y, xs.z + xr.z, xs.w + xr.w};
    float s = x[0] + x[1] + x[2] + x[3];
    float q = x[0] * x[0] + x[1] * x[1] + x[2] * x[2] + x[3] * x[3];
#pragma unroll
    for (int d = 1; d < 64; d <<= 1) {
        s += __shfl_xor(s, d);
        q += __shfl_xor(q, d);
    }
    float mean = s * (1.f / 256.f);
    float var = q * (1.f / 256.f) - mean * mean;
    float rstd = rsqrtf(var + 1e-5f);
    float4 gv = *reinterpret_cast<const float4*>(g + c);
    float4 bv = *reinterpret_cast<const float4*>(be + c);
    float y0 = (x[0] - mean) * rstd * gv.x + bv.x;
    float y1 = (x[1] - mean) * rstd * gv.y + bv.y;
    float y2 = (x[2] - mean) * rstd * gv.z + bv.z;
    float y3 = (x[3] - mean) * rstd * gv.w + bv.w;
    *reinterpret_cast<float4*>(outf + (size_t)r * C_DIM + c) = make_float4(y0, y1, y2, y3);
    *reinterpret_cast<ushort4*>(outb + (size_t)r * C_DIM + c) =
        make_ushort4(f2bf(y0), f2bf(y1), f2bf(y2), f2bf(y3));
}

__global__ __launch_bounds__(256) void ln2_kernel(const float* __restrict__ rec1f,
                                                  const float* __restrict__ ffn,
                                                  const float* __restrict__ g,
                                                  const float* __restrict__ be,
                                                  float* __restrict__ out) {
    int r = blockIdx.x * 4 + (threadIdx.x >> 6);
    int lane = threadIdx.x & 63;
    int c = lane * 4;
    size_t base = (size_t)r * C_DIM + c;
    float4 xa = *reinterpret_cast<const float4*>(rec1f + base);
    float4 xb = *reinterpret_cast<const float4*>(ffn + base);
    float x[4] = {xa.x + xb.x, xa.y + xb.y, xa.z + xb.z, xa.w + xb.w};
    float s = x[0] + x[1] + x[2] + x[3];
    float q = x[0] * x[0] + x[1] * x[1] + x[2] * x[2] + x[3] * x[3];
#pragma unroll
    for (int d = 1; d < 64; d <<= 1) {
        s += __shfl_xor(s, d);
        q += __shfl_xor(q, d);
    }
    float mean = s * (1.f / 256.f);
    float var = q * (1.f / 256.f) - mean * mean;
    float rstd = rsqrtf(var + 1e-5f);
    float4 gv = *reinterpret_cast<const float4*>(g + c);
    float4 bv = *reinterpret_cast<const float4*>(be + c);
    *reinterpret_cast<float4*>(out + base) = make_float4(
        (x[0] - mean) * rstd * gv.x + bv.x,
        (x[1] - mean) * rstd * gv.y + bv.y,
        (x[2] - mean) * rstd * gv.z + bv.z,
        (x[3] - mean) * rstd * gv.w + bv.w);
}

// ---------------- launch ----------------

extern "C" void kernel_launch(void* const* d_in, const int* in_sizes, int n_in,
                              void* d_out, int out_size, void* d_ws, size_t ws_size,
                              hipStream_t stream) {
    const float* src   = (const float*)d_in[0];
    const float* match = (const float*)d_in[1];
    const float* pos   = (const float*)d_in[2];
    const float* mask  = (const float*)d_in[3];
    const float* Wagg  = (const float*)d_in[4];
    const float* bagg  = (const float*)d_in[5];
    const float* W1    = (const float*)d_in[6];
    const float* b1    = (const float*)d_in[7];
    const float* W2    = (const float*)d_in[8];
    const float* b2    = (const float*)d_in[9];
    const float* g1    = (const float*)d_in[10];
    const float* be1   = (const float*)d_in[11];
    const float* g2    = (const float*)d_in[12];
    const float* be2   = (const float*)d_in[13];

    char* ws = (char*)d_ws;
    unsigned short* qb    = (unsigned short*)(ws + 0);          //  4 MB (B,N,C) bf16 pre-scaled
    unsigned short* kb    = (unsigned short*)(ws + 4194304);    // 16 MB (K*B,N,C) bf16
    unsigned short* vfrag = (unsigned short*)(ws + 20971520);   // 16 MB V fragment tiles
    unsigned short* att   = (unsigned short*)(ws + 37748736);   // 16 MB (B,N,K*C) bf16
    float*          rec_t = (float*)(ws + 57147392);            // 8 MB (B*N,C) f32
    float*          rec1f = (float*)(ws + 65536000);            // 8 MB (N*B,C) f32
    unsigned short* rec1b = (unsigned short*)(ws + 73924608);   // 4 MB bf16
    unsigned short* WaggT = (unsigned short*)(ws + 54525952);   // 0.5 MB
    unsigned short* W1T   = (unsigned short*)(ws + 55050240);   // 1 MB
    unsigned short* W2T   = (unsigned short*)(ws + 56098816);   // 1 MB
    unsigned short* hid   = (unsigned short*)(ws + 4194304);    // 32 MB, aliases kb+vfrag
    float*          ffn   = (float*)(ws + 57147392);            // 8 MB, aliases rec_t
    float* outp = (float*)d_out;

    prep_q_kernel<<<2048, 256, 0, stream>>>(src, pos, qb);
    prep_kv_kernel<<<512, 256, 0, stream>>>(match, pos, kb, vfrag);
    transpose_w_kernel<<<1024, 256, 0, stream>>>(Wagg, WaggT, K_HEADS * C_DIM, C_DIM);
    transpose_w_kernel<<<2048, 256, 0, stream>>>(W1, W1T, C_DIM, FF_DIM);
    transpose_w_kernel<<<2048, 256, 0, stream>>>(W2, W2T, FF_DIM, C_DIM);

    attn_kernel<<<512, 256, 0, stream>>>(qb, kb, vfrag, mask, att);

    gemm_bt_kernel<64, 128, 0, 0><<<dim3(2, 128), 256, 0, stream>>>(
        att, WaggT, bagg, rec_t, nullptr, B_SZ * N_SEQ, C_DIM, K_HEADS * C_DIM);
    ln1_kernel<<<2048, 256, 0, stream>>>(src, rec_t, g1, be1, rec1f, rec1b);
    gemm_bt_kernel<128, 128, 1, 1><<<dim3(16, 64), 256, 0, stream>>>(
        rec1b, W1T, b1, nullptr, hid, N_SEQ * B_SZ, FF_DIM, C_DIM);
    gemm_bt_kernel<64, 128, 0, 0><<<dim3(2, 128), 256, 0, stream>>>(
        hid, W2T, b2, ffn, nullptr, N_SEQ * B_SZ, C_DIM, FF_DIM);
    ln2_kernel<<<2048, 256, 0, stream>>>(rec1f, ffn, g2, be2, outp);
}

// Round 10
// 145.102 us; speedup vs baseline: 1.9286x; 1.0998x over previous
//
#include <hip/hip_runtime.h>

#define N_SEQ 1024
#define B_SZ 8
#define C_DIM 256
#define K_HEADS 4
#define FF_DIM 2048

typedef short s16x8 __attribute__((ext_vector_type(8)));
typedef float f32x4v __attribute__((ext_vector_type(4)));

#define GLOAD_LDS16(src, dst)                                                              \
    __builtin_amdgcn_global_load_lds((const __attribute__((address_space(1))) void*)(src), \
                                     (__attribute__((address_space(3))) void*)(dst), 16, 0, 0)

__device__ __forceinline__ unsigned short f2bf(float f) {
    unsigned u = __builtin_bit_cast(unsigned, f);
    u += 0x7FFFu + ((u >> 16) & 1u);
    return (unsigned short)(u >> 16);
}
__device__ __forceinline__ float bf2f(unsigned short h) {
    unsigned u = ((unsigned)h) << 16;
    return __builtin_bit_cast(float, u);
}

// ---------------- prep kernels ----------------

__global__ __launch_bounds__(256) void prep_q_kernel(const float* __restrict__ src,
                                                     const float* __restrict__ pos,
                                                     unsigned short* __restrict__ qb) {
    int t = blockIdx.x * 256 + threadIdx.x;
    int i4 = t * 4;
    float4 s = *reinterpret_cast<const float4*>(src + i4);
    float4 p = *reinterpret_cast<const float4*>(pos + i4);
    int n = i4 >> 11;
    int rem = i4 & 2047;
    int b = rem >> 8;
    int c = rem & 255;
    int out = (b * N_SEQ + n) * C_DIM + c;
    *reinterpret_cast<ushort4*>(qb + out) = make_ushort4(
        f2bf((s.x + p.x) * 0.0625f), f2bf((s.y + p.y) * 0.0625f),
        f2bf((s.z + p.z) * 0.0625f), f2bf((s.w + p.w) * 0.0625f));
}

// One block per (k,b,ntile of 64): writes kb row-major (+pos) and V in
// per-wave-linear fragment order: vfrag[pr][tile32][ct=16][lane=64][e=8].
__global__ __launch_bounds__(256) void prep_kv_kernel(const float* __restrict__ matched,
                                                      const float* __restrict__ pos,
                                                      unsigned short* __restrict__ kb,
                                                      unsigned short* __restrict__ vfrag) {
    __shared__ unsigned short Vl[64][256];
    int blk = blockIdx.x;
    int nt = blk & 15, pr = blk >> 4;          // pr = k*8+b
    int k = pr >> 3, b = pr & 7;
    int n0 = nt * 64;
    int t = threadIdx.x;
    int c4 = (t & 63) * 4;
#pragma unroll
    for (int r = 0; r < 16; r++) {
        int nl = (t >> 6) * 16 + r;
        int n = n0 + nl;
        size_t mi = ((size_t)(k * N_SEQ + n) * B_SZ + b) * C_DIM + c4;
        float4 m = *reinterpret_cast<const float4*>(matched + mi);
        float4 p = *reinterpret_cast<const float4*>(pos + ((size_t)n * B_SZ + b) * C_DIM + c4);
        *reinterpret_cast<ushort4*>(kb + ((size_t)pr * N_SEQ + n) * C_DIM + c4) =
            make_ushort4(f2bf(m.x + p.x), f2bf(m.y + p.y), f2bf(m.z + p.z), f2bf(m.w + p.w));
        *reinterpret_cast<ushort4*>(&Vl[nl][c4]) =
            make_ushort4(f2bf(m.x), f2bf(m.y), f2bf(m.z), f2bf(m.w));
    }
    __syncthreads();
#pragma unroll
    for (int h = 0; h < 2; h++) {
        unsigned short* tb = vfrag + ((size_t)(pr * 32 + nt * 2 + h)) * 8192;
#pragma unroll
        for (int g = 0; g < 4; g++) {
            int c2 = t + 256 * g;                // chunk index 0..1023
            int ct = c2 >> 6;
            int lane2 = c2 & 63;
            int l152 = lane2 & 15, lg2 = lane2 >> 4;
            s16x8 v;
#pragma unroll
            for (int e = 0; e < 8; e++)
                v[e] = (short)Vl[h * 32 + lg2 * 8 + e][ct * 16 + l152];
            *reinterpret_cast<s16x8*>(tb + (size_t)c2 * 8) = v;
        }
    }
}

// merged weight transposes: Wt[c*R+r] = bf16(W[r*Cn+c]); all R,Cn powers of 2
__global__ __launch_bounds__(256) void transpose_all_kernel(const float* __restrict__ Wagg,
                                                            const float* __restrict__ W1,
                                                            const float* __restrict__ W2,
                                                            unsigned short* __restrict__ WaggT,
                                                            unsigned short* __restrict__ W1T,
                                                            unsigned short* __restrict__ W2T) {
    int idx = blockIdx.x * 256 + threadIdx.x;
    if (idx < 262144) {                        // Wagg: R=1024, Cn=256
        int c = idx >> 10, r = idx & 1023;
        WaggT[idx] = f2bf(Wagg[(size_t)r * 256 + c]);
    } else if (idx < 786432) {                 // W1: R=256, Cn=2048
        int i = idx - 262144;
        int c = i >> 8, r = i & 255;
        W1T[i] = f2bf(W1[(size_t)r * 2048 + c]);
    } else {                                   // W2: R=2048, Cn=256
        int i = idx - 786432;
        int c = i >> 11, r = i & 2047;
        W2T[i] = f2bf(W2[(size_t)r * 256 + c]);
    }
}

// ---------------- flash attention (single-pass, cooperative ch-split PV) ----------------
// grid = 512 blocks x 256 threads. Block = 64 q (4 waves). Wave w: QK+softmax for
// q-tile w; PV for channel quarter [w*64, w*64+64) of ALL 4 q-tiles (P via LDS).
__global__ __launch_bounds__(256, 2) void attn_kernel(const unsigned short* __restrict__ qb,
                                                      const unsigned short* __restrict__ kb,
                                                      const unsigned short* __restrict__ vfrag,
                                                      const float* __restrict__ mask,
                                                      unsigned short* __restrict__ att) {
    __shared__ unsigned short Kl[2][8192];       // 32 KB: K tile, XOR-swizzled content
    __shared__ unsigned short Psh[2][4][16][40]; // 10 KB: P exchange, dbuf
    __shared__ float scl[2][4][17];              // rescale factors, dbuf
    __shared__ float lrex[4][17];                // final l exchange

    int bx = blockIdx.x;
    int b = bx & 7;                              // XCD owns one batch's mask/Q
    int r2 = bx >> 3;
    int kidx = r2 & 3;
    int qtb = r2 >> 2;                           // 0..15 (64-q tiles)
    int pr = kidx * 8 + b;

    int tid = threadIdx.x, wid = tid >> 6, lane = tid & 63;
    int l15 = lane & 15, lg = lane >> 4;
    int q0 = qtb * 64 + wid * 16;                // wave's own q-tile base

    // Q fragments (wave's own 16 q)
    s16x8 qf[8];
    const unsigned short* qrow = qb + ((size_t)(b * N_SEQ + q0 + l15)) * C_DIM + lg * 8;
#pragma unroll
    for (int cc = 0; cc < 8; cc++) qf[cc] = *reinterpret_cast<const s16x8*>(qrow + cc * 32);

    f32x4v oacc[16];
#pragma unroll
    for (int i = 0; i < 16; i++) oacc[i] = (f32x4v){0.f, 0.f, 0.f, 0.f};
    float mrun = -3e38f, lrun = 0.f;

    const unsigned short* kbp = kb + (size_t)pr * N_SEQ * C_DIM;
    const unsigned short* vfp = vfrag + (size_t)pr * 32 * 8192 + lane * 8;
    const float* mrow = mask + ((size_t)b * N_SEQ + q0 + l15) * N_SEQ;

    auto stage_k = [&](int kv0, unsigned short* buf) {
#pragma unroll
        for (int i = 0; i < 4; i++) {
            int ch = (wid * 4 + i) * 64 + lane;
            int r = ch >> 5;
            int ce = ((ch & 31) * 8) ^ ((r & 7) << 3);
            GLOAD_LDS16(kbp + (size_t)(kv0 + r) * C_DIM + ce, &buf[(wid * 4 + i) * 512]);
        }
    };

    // prologue
    stage_k(0, &Kl[0][0]);
    f32x4v mc0 = *reinterpret_cast<const f32x4v*>(mrow + lg * 4);
    f32x4v mc1 = *reinterpret_cast<const f32x4v*>(mrow + 16 + lg * 4);

    int swz = (l15 & 7) << 3;
    for (int t = 0; t < 32; t++) {
        int cur = t & 1;
        int kv0 = t * 32;
        __syncthreads();                         // (A) K[t] ready; Psh[cur] free
        if (t + 1 < 32) stage_k(kv0 + 32, &Kl[cur ^ 1][0]);

        // V fragments for this wave's channel quarter (4 coalesced 1KB loads, L2)
        const unsigned short* vsrc = vfp + (size_t)t * 8192;
        s16x8 vreg[4];
#pragma unroll
        for (int c = 0; c < 4; c++)
            vreg[c] = *reinterpret_cast<const s16x8*>(vsrc + (wid * 4 + c) * 512);

        // S^T = K Q^T (own q-tile)
        f32x4v s0 = {0.f, 0.f, 0.f, 0.f}, s1 = {0.f, 0.f, 0.f, 0.f};
        const unsigned short* KlB = &Kl[cur][0];
        __builtin_amdgcn_s_setprio(1);
#pragma unroll
        for (int cc = 0; cc < 8; cc++) {
            s16x8 k0 = *reinterpret_cast<const s16x8*>(KlB + l15 * 256 + ((cc * 32 + lg * 8) ^ swz));
            s16x8 k1 = *reinterpret_cast<const s16x8*>(KlB + (16 + l15) * 256 + ((cc * 32 + lg * 8) ^ swz));
            s0 = __builtin_amdgcn_mfma_f32_16x16x32_bf16(k0, qf[cc], s0, 0, 0, 0);
            s1 = __builtin_amdgcn_mfma_f32_16x16x32_bf16(k1, qf[cc], s1, 0, 0, 0);
        }
        __builtin_amdgcn_s_setprio(0);
#pragma unroll
        for (int jj = 0; jj < 4; jj++) { s0[jj] += mc0[jj]; s1[jj] += mc1[jj]; }
        if (t + 1 < 32) {
            mc0 = *reinterpret_cast<const f32x4v*>(mrow + kv0 + 32 + lg * 4);
            mc1 = *reinterpret_cast<const f32x4v*>(mrow + kv0 + 48 + lg * 4);
        }

        // online softmax over kv (in-lane 8 + xor 16/32)
        float pm = fmaxf(fmaxf(fmaxf(s0[0], s0[1]), fmaxf(s0[2], s0[3])),
                         fmaxf(fmaxf(s1[0], s1[1]), fmaxf(s1[2], s1[3])));
        pm = fmaxf(pm, __shfl_xor(pm, 16));
        pm = fmaxf(pm, __shfl_xor(pm, 32));
        float sc = 1.0f;
        if (__any(pm > mrun + 8.f)) {            // defer-max
            float mn = fmaxf(mrun, pm);
            sc = __expf(mrun - mn);
            mrun = mn;
        }
        float p0[4], p1[4];
#pragma unroll
        for (int jj = 0; jj < 4; jj++) {
            p0[jj] = __expf(s0[jj] - mrun);
            p1[jj] = __expf(s1[jj] - mrun);
        }
        float ps = (p0[0] + p0[1]) + (p0[2] + p0[3]) + (p1[0] + p1[1]) + (p1[2] + p1[3]);
        ps += __shfl_xor(ps, 16);
        ps += __shfl_xor(ps, 32);
        lrun = lrun * sc + ps;

        // publish P (A-fragment layout) + rescale factor
        *reinterpret_cast<ushort4*>(&Psh[cur][wid][l15][lg * 4]) =
            make_ushort4(f2bf(p0[0]), f2bf(p0[1]), f2bf(p0[2]), f2bf(p0[3]));
        *reinterpret_cast<ushort4*>(&Psh[cur][wid][l15][16 + lg * 4]) =
            make_ushort4(f2bf(p1[0]), f2bf(p1[1]), f2bf(p1[2]), f2bf(p1[3]));
        if (lane < 16) scl[cur][wid][lane] = sc;
        __syncthreads();                         // (B) P + sc visible

        // PV: this wave's 64 channels x all 4 q-tiles
        __builtin_amdgcn_s_setprio(1);
#pragma unroll
        for (int j = 0; j < 4; j++) {
            float scj = scl[cur][j][l15];
            s16x8 pf = *reinterpret_cast<const s16x8*>(&Psh[cur][j][l15][lg * 8]);
            if (__any(scj != 1.0f)) {            // wave-uniform: rescale only when needed
#pragma unroll
                for (int c = 0; c < 4; c++)
#pragma unroll
                    for (int jj = 0; jj < 4; jj++) oacc[j * 4 + c][jj] *= scj;
            }
#pragma unroll
            for (int c = 0; c < 4; c++) {
                int idx = j * 4 + c;
                oacc[idx] = __builtin_amdgcn_mfma_f32_16x16x32_bf16(vreg[c], pf, oacc[idx], 0, 0, 0);
            }
        }
        __builtin_amdgcn_s_setprio(0);
    }

    // epilogue: exchange l, normalize, write O
    if (lane < 16) lrex[wid][lane] = lrun;
    __syncthreads();
#pragma unroll
    for (int j = 0; j < 4; j++) {
        float invj = 1.0f / lrex[j][l15];
#pragma unroll
        for (int c = 0; c < 4; c++) {
            int idx = j * 4 + c;
            size_t orow = ((size_t)(b * N_SEQ + qtb * 64 + j * 16 + l15)) * (K_HEADS * C_DIM)
                          + kidx * C_DIM + wid * 64 + c * 16 + lg * 4;
            *reinterpret_cast<ushort4*>(att + orow) =
                make_ushort4(f2bf(oacc[idx][0] * invj), f2bf(oacc[idx][1] * invj),
                             f2bf(oacc[idx][2] * invj), f2bf(oacc[idx][3] * invj));
        }
    }
}

// ---------------- GEMM: C = A(MxK) * Bt(NxK)^T + bias, optional split-K ----------------
template <int BM, int BN, int RELU, int OUTBF, int SPLITK>
__global__ __launch_bounds__(256) void gemm_bt_kernel(const unsigned short* __restrict__ A,
                                                      const unsigned short* __restrict__ Bt,
                                                      const float* __restrict__ bias,
                                                      float* __restrict__ Cf0,
                                                      float* __restrict__ Cf1,
                                                      unsigned short* __restrict__ Cb,
                                                      int M, int Nn, int Kd) {
    constexpr int WAVES_N = (BM == 128) ? 2 : 4;
    constexpr int WN = BN / WAVES_N;
    constexpr int NT = WN / 16;
    constexpr int TILE = (BM + BN) * 64;
    constexpr int CALLS = (BM + BN) / 32;
    __shared__ unsigned short Sl[2][TILE];
    int tm0 = blockIdx.y * BM, tn0 = blockIdx.x * BN;
    int kz = (SPLITK == 2) ? blockIdx.z : 0;
    int kbase = kz * (Kd / SPLITK);
    int tid = threadIdx.x, wid = tid >> 6, lane = tid & 63;
    int l15 = lane & 15, lg = lane >> 4;
    int wm = (wid / WAVES_N) * 64, wn = (wid % WAVES_N) * WN;

    f32x4v acc[4][NT];
#pragma unroll
    for (int i = 0; i < 4; i++)
#pragma unroll
        for (int j = 0; j < NT; j++) acc[i][j] = (f32x4v){0.f, 0.f, 0.f, 0.f};

    auto stage = [&](int k0, unsigned short* buf) {
#pragma unroll
        for (int i = 0; i < CALLS; i++) {
            int chb = (i * 4 + wid) * 64;
            int ch = chb + lane;
            const unsigned short* src;
            if (chb < BM * 8) {
                int r = ch >> 3;
                int c8 = ((ch & 7) * 8) ^ ((r & 7) << 3);
                src = A + (size_t)(tm0 + r) * Kd + k0 + c8;
            } else {
                int ch2 = ch - BM * 8;
                int r = ch2 >> 3;
                int c8 = ((ch2 & 7) * 8) ^ ((r & 7) << 3);
                src = Bt + (size_t)(tn0 + r) * Kd + k0 + c8;
            }
            GLOAD_LDS16(src, buf + chb * 8);
        }
    };

    stage(kbase, &Sl[0][0]);
    int nk = (Kd / SPLITK) >> 6;
    int swz = (l15 & 7) << 3;
    for (int kt = 0; kt < nk; kt++) {
        int cur = kt & 1;
        __syncthreads();
        if (kt + 1 < nk) stage(kbase + (kt + 1) * 64, &Sl[cur ^ 1][0]);
        const unsigned short* SA = &Sl[cur][0];
        const unsigned short* SB = SA + BM * 64;
        s16x8 af[4][2], bf[NT][2];
#pragma unroll
        for (int mt = 0; mt < 4; mt++)
#pragma unroll
            for (int h = 0; h < 2; h++)
                af[mt][h] = *reinterpret_cast<const s16x8*>(
                    SA + (wm + mt * 16 + l15) * 64 + ((h * 32 + lg * 8) ^ swz));
#pragma unroll
        for (int nt = 0; nt < NT; nt++)
#pragma unroll
            for (int h = 0; h < 2; h++)
                bf[nt][h] = *reinterpret_cast<const s16x8*>(
                    SB + (wn + nt * 16 + l15) * 64 + ((h * 32 + lg * 8) ^ swz));
        __builtin_amdgcn_s_setprio(1);
#pragma unroll
        for (int mt = 0; mt < 4; mt++)
#pragma unroll
            for (int nt = 0; nt < NT; nt++) {
                acc[mt][nt] = __builtin_amdgcn_mfma_f32_16x16x32_bf16(af[mt][0], bf[nt][0], acc[mt][nt], 0, 0, 0);
                acc[mt][nt] = __builtin_amdgcn_mfma_f32_16x16x32_bf16(af[mt][1], bf[nt][1], acc[mt][nt], 0, 0, 0);
            }
        __builtin_amdgcn_s_setprio(0);
    }

    float* Cf = (SPLITK == 2 && kz) ? Cf1 : Cf0;
#pragma unroll
    for (int mt = 0; mt < 4; mt++) {
#pragma unroll
        for (int nt = 0; nt < NT; nt++) {
#pragma unroll
            for (int j = 0; j < 4; j++) {
                int row = tm0 + wm + mt * 16 + lg * 4 + j;
                int col = tn0 + wn + nt * 16 + l15;
                float bv = (SPLITK == 2 && kz) ? 0.f : bias[col];
                float v = acc[mt][nt][j] + bv;
                if (RELU) v = fmaxf(v, 0.f);
                if (OUTBF) Cb[(size_t)row * Nn + col] = f2bf(v);
                else       Cf[(size_t)row * Nn + col] = v;
            }
        }
    }
}

// ---------------- fused residual + LayerNorm ----------------
// rows r = n*B + b ; x = src[r] + p0[(b,n)] + p1[(b,n)] ; output bf16 only
__global__ __launch_bounds__(256) void ln1_kernel(const float* __restrict__ src,
                                                  const float* __restrict__ p0,
                                                  const float* __restrict__ p1,
                                                  const float* __restrict__ g,
                                                  const float* __restrict__ be,
                                                  unsigned short* __restrict__ outb) {
    int r = blockIdx.x * 4 + (threadIdx.x >> 6);
    int lane = threadIdx.x & 63;
    int n = r >> 3, b = r & 7;
    int c = lane * 4;
    size_t tb_ = ((size_t)(b * N_SEQ + n)) * C_DIM + c;
    float4 xs = *reinterpret_cast<const float4*>(src + (size_t)r * C_DIM + c);
    float4 xa = *reinterpret_cast<const float4*>(p0 + tb_);
    float4 xb = *reinterpret_cast<const float4*>(p1 + tb_);
    float x[4] = {xs.x + xa.x + xb.x, xs.y + xa.y + xb.y,
                  xs.z + xa.z + xb.z, xs.w + xa.w + xb.w};
    float s = x[0] + x[1] + x[2] + x[3];
    float q = x[0] * x[0] + x[1] * x[1] + x[2] * x[2] + x[3] * x[3];
#pragma unroll
    for (int d = 1; d < 64; d <<= 1) {
        s += __shfl_xor(s, d);
        q += __shfl_xor(q, d);
    }
    float mean = s * (1.f / 256.f);
    float var = q * (1.f / 256.f) - mean * mean;
    float rstd = rsqrtf(var + 1e-5f);
    float4 gv = *reinterpret_cast<const float4*>(g + c);
    float4 bv = *reinterpret_cast<const float4*>(be + c);
    *reinterpret_cast<ushort4*>(outb + (size_t)r * C_DIM + c) = make_ushort4(
        f2bf((x[0] - mean) * rstd * gv.x + bv.x), f2bf((x[1] - mean) * rstd * gv.y + bv.y),
        f2bf((x[2] - mean) * rstd * gv.z + bv.z), f2bf((x[3] - mean) * rstd * gv.w + bv.w));
}

// x = bf16 rec1 + ffn_p0 + ffn_p1 ; out f32
__global__ __launch_bounds__(256) void ln2_kernel(const unsigned short* __restrict__ rec1b,
                                                  const float* __restrict__ p0,
                                                  const float* __restrict__ p1,
                                                  const float* __restrict__ g,
                                                  const float* __restrict__ be,
                                                  float* __restrict__ out) {
    int r = blockIdx.x * 4 + (threadIdx.x >> 6);
    int lane = threadIdx.x & 63;
    int c = lane * 4;
    size_t base = (size_t)r * C_DIM + c;
    ushort4 xr = *reinterpret_cast<const ushort4*>(rec1b + base);
    float4 xa = *reinterpret_cast<const float4*>(p0 + base);
    float4 xb = *reinterpret_cast<const float4*>(p1 + base);
    float x[4] = {bf2f(xr.x) + xa.x + xb.x, bf2f(xr.y) + xa.y + xb.y,
                  bf2f(xr.z) + xa.z + xb.z, bf2f(xr.w) + xa.w + xb.w};
    float s = x[0] + x[1] + x[2] + x[3];
    float q = x[0] * x[0] + x[1] * x[1] + x[2] * x[2] + x[3] * x[3];
#pragma unroll
    for (int d = 1; d < 64; d <<= 1) {
        s += __shfl_xor(s, d);
        q += __shfl_xor(q, d);
    }
    float mean = s * (1.f / 256.f);
    float var = q * (1.f / 256.f) - mean * mean;
    float rstd = rsqrtf(var + 1e-5f);
    float4 gv = *reinterpret_cast<const float4*>(g + c);
    float4 bv = *reinterpret_cast<const float4*>(be + c);
    *reinterpret_cast<float4*>(out + base) = make_float4(
        (x[0] - mean) * rstd * gv.x + bv.x,
        (x[1] - mean) * rstd * gv.y + bv.y,
        (x[2] - mean) * rstd * gv.z + bv.z,
        (x[3] - mean) * rstd * gv.w + bv.w);
}

// ---------------- launch ----------------

extern "C" void kernel_launch(void* const* d_in, const int* in_sizes, int n_in,
                              void* d_out, int out_size, void* d_ws, size_t ws_size,
                              hipStream_t stream) {
    const float* src   = (const float*)d_in[0];
    const float* match = (const float*)d_in[1];
    const float* pos   = (const float*)d_in[2];
    const float* mask  = (const float*)d_in[3];
    const float* Wagg  = (const float*)d_in[4];
    const float* bagg  = (const float*)d_in[5];
    const float* W1    = (const float*)d_in[6];
    const float* b1    = (const float*)d_in[7];
    const float* W2    = (const float*)d_in[8];
    const float* b2    = (const float*)d_in[9];
    const float* g1    = (const float*)d_in[10];
    const float* be1   = (const float*)d_in[11];
    const float* g2    = (const float*)d_in[12];
    const float* be2   = (const float*)d_in[13];

    char* ws = (char*)d_ws;
    unsigned short* qb    = (unsigned short*)(ws + 0);          //  4 MB (prep->attn)
    unsigned short* kb    = (unsigned short*)(ws + 4194304);    // 16 MB (prep->attn)
    unsigned short* vfrag = (unsigned short*)(ws + 20971520);   // 16 MB (prep->attn)
    unsigned short* att   = (unsigned short*)(ws + 37748736);   // 16 MB (attn->gemm1)
    unsigned short* WaggT = (unsigned short*)(ws + 54525952);   // 0.5 MB
    unsigned short* W1T   = (unsigned short*)(ws + 55050240);   // 1 MB
    unsigned short* W2T   = (unsigned short*)(ws + 56098816);   // 1 MB
    float*          rec_p0 = (float*)(ws + 57147392);           // 8 MB (gemm1->ln1)
    float*          rec_p1 = (float*)(ws + 65536000);           // 8 MB (gemm1->ln1)
    // post-attn aliases:
    unsigned short* rec1b = (unsigned short*)(ws + 0);          // 4 MB over qb (ln1->ln2)
    unsigned short* hid   = (unsigned short*)(ws + 4194304);    // 32 MB over kb+vfrag (gemm2->gemm3)
    float*          ffn_p0 = rec_p0;                            // reuse after ln1
    float*          ffn_p1 = rec_p1;
    float* outp = (float*)d_out;

    prep_q_kernel<<<2048, 256, 0, stream>>>(src, pos, qb);
    prep_kv_kernel<<<512, 256, 0, stream>>>(match, pos, kb, vfrag);
    transpose_all_kernel<<<5120, 256, 0, stream>>>(Wagg, W1, W2, WaggT, W1T, W2T);

    attn_kernel<<<512, 256, 0, stream>>>(qb, kb, vfrag, mask, att);

    // rec = att @ Wagg + bagg   (split-K x2: K=1024 -> 2x512)
    gemm_bt_kernel<64, 128, 0, 0, 2><<<dim3(2, 128, 2), 256, 0, stream>>>(
        att, WaggT, bagg, rec_p0, rec_p1, nullptr, B_SZ * N_SEQ, C_DIM, K_HEADS * C_DIM);
    ln1_kernel<<<2048, 256, 0, stream>>>(src, rec_p0, rec_p1, g1, be1, rec1b);
    // hid = relu(rec1 @ W1 + b1)
    gemm_bt_kernel<128, 128, 1, 1, 1><<<dim3(16, 64), 256, 0, stream>>>(
        rec1b, W1T, b1, nullptr, nullptr, hid, N_SEQ * B_SZ, FF_DIM, C_DIM);
    // ffn = hid @ W2 + b2   (split-K x2: K=2048 -> 2x1024)
    gemm_bt_kernel<64, 128, 0, 0, 2><<<dim3(2, 128, 2), 256, 0, stream>>>(
        hid, W2T, b2, ffn_p0, ffn_p1, nullptr, N_SEQ * B_SZ, C_DIM, FF_DIM);
    ln2_kernel<<<2048, 256, 0, stream>>>(rec1b, ffn_p0, ffn_p1, g2, be2, outp);
}